// Round 1
// baseline (931.156 us; speedup 1.0000x reference)
//
#include <hip/hip_runtime.h>

#define D 512
#define H 8
#define NL 3
#define FFD 2048
#define HID 256
#define BAND 17
#define BATCH 16
#define SEQ 512
#define MTOK (BATCH * SEQ)   // 8192
#define NOUT 101             // 12 + 89

typedef unsigned short u16;
typedef __attribute__((ext_vector_type(8))) short short8;     // bf16x8 MFMA frag
typedef __attribute__((ext_vector_type(4))) float f32x4;
typedef __attribute__((ext_vector_type(8))) unsigned short u16x8;

__device__ inline float bf2f(u16 u) {
    union { unsigned int i; float f; } x; x.i = ((unsigned int)u) << 16; return x.f;
}
__device__ inline u16 f2bf(float f) {
    union { float f; unsigned int i; } x; x.f = f;
    unsigned int r = x.i + 0x7fffu + ((x.i >> 16) & 1u);
    return (u16)(r >> 16);
}

// ---------------------------------------------------------------------------
// Generic bf16 MFMA GEMM: C(MxN) = A(MxK) @ B(NxK)^T + bias, optional relu.
// A, B bf16 row-major; C written as fp32 (Cf) and/or bf16 (Cb).
// M must be a multiple of 128; K a multiple of 32; N arbitrary (guarded).
// 128x128 tile, BK=32, 4 waves, each wave 64x64 via 4x4 of 16x16x32 MFMA.
// ---------------------------------------------------------------------------
#define BM 128
#define BN 128
#define BK 32
#define LDT 40   // LDS row stride in u16 (+8 pad: 80B stride spreads banks)

__global__ __launch_bounds__(256) void gemm_kernel(
    const u16* __restrict__ A, int lda,
    const u16* __restrict__ B, int ldb,
    const float* __restrict__ bias,
    float* __restrict__ Cf, int ldcf,
    u16* __restrict__ Cb, int ldcb,
    int M, int N, int K, int relu)
{
    __shared__ u16 As[BM * LDT];
    __shared__ u16 Bs[BN * LDT];
    const int tid  = threadIdx.x;
    const int lane = tid & 63;
    const int wave = tid >> 6;
    const int wr = wave >> 1, wc = wave & 1;
    const int m0 = blockIdx.y * BM, n0 = blockIdx.x * BN;

    f32x4 acc[4][4] = {};

    const int kcol = (lane >> 4) << 3;   // 0,8,16,24
    const int frow = lane & 15;

    for (int k0 = 0; k0 < K; k0 += BK) {
        // stage 128x32 A and B tiles: 512 slots of 8 bf16, 256 threads x 2
        #pragma unroll
        for (int s = 0; s < 2; ++s) {
            int slot = tid + s * 256;        // 0..511
            int r  = slot >> 2;              // 0..127
            int kg = (slot & 3) << 3;        // 0,8,16,24
            {
                const u16* src = A + (size_t)(m0 + r) * lda + (k0 + kg);
                *(u16x8*)&As[r * LDT + kg] = *(const u16x8*)src;
            }
            {
                int gn = n0 + r;
                u16x8 v = {0, 0, 0, 0, 0, 0, 0, 0};
                if (gn < N) v = *(const u16x8*)(B + (size_t)gn * ldb + (k0 + kg));
                *(u16x8*)&Bs[r * LDT + kg] = v;
            }
        }
        __syncthreads();

        short8 af[4], bfr[4];
        #pragma unroll
        for (int i = 0; i < 4; ++i)
            af[i] = *(const short8*)&As[(wr * 64 + i * 16 + frow) * LDT + kcol];
        #pragma unroll
        for (int j = 0; j < 4; ++j)
            bfr[j] = *(const short8*)&Bs[(wc * 64 + j * 16 + frow) * LDT + kcol];

        #pragma unroll
        for (int i = 0; i < 4; ++i)
            #pragma unroll
            for (int j = 0; j < 4; ++j)
                acc[i][j] = __builtin_amdgcn_mfma_f32_16x16x32_bf16(af[i], bfr[j], acc[i][j], 0, 0, 0);
        __syncthreads();
    }

    // epilogue: C/D layout col = lane&15, row = (lane>>4)*4 + reg  [m89/m91]
    const int crow0 = (lane >> 4) * 4;
    const int ccol  = lane & 15;
    #pragma unroll
    for (int j = 0; j < 4; ++j) {
        int gcol = n0 + wc * 64 + j * 16 + ccol;
        if (gcol >= N) continue;
        float bv = bias ? bias[gcol] : 0.f;
        #pragma unroll
        for (int i = 0; i < 4; ++i) {
            #pragma unroll
            for (int r = 0; r < 4; ++r) {
                int grow = m0 + wr * 64 + i * 16 + crow0 + r;
                float v = acc[i][j][r] + bv;
                if (relu) v = fmaxf(v, 0.f);
                if (Cf) Cf[(size_t)grow * ldcf + gcol] = v;
                if (Cb) Cb[(size_t)grow * ldcb + gcol] = f2bf(v);
            }
        }
    }
}

// ---------------------------------------------------------------------------
// Banded attention: one wave per (b, i, h); window [i-16, i]; online softmax.
// qkv bf16 rows of 1536 (q|k|v); writes o bf16 (M x 512).
// ---------------------------------------------------------------------------
__global__ __launch_bounds__(256) void attn_kernel(
    const u16* __restrict__ qkv, const unsigned char* __restrict__ pad,
    u16* __restrict__ o)
{
    int gw   = blockIdx.x * 4 + (threadIdx.x >> 6);
    int lane = threadIdx.x & 63;
    int h = gw & (H - 1);
    int t = gw >> 3;            // b*512 + i
    int i = t & (SEQ - 1);
    int b = t >> 9;
    const u16* base = qkv + (size_t)b * SEQ * (3 * D);

    float q = bf2f(base[(size_t)i * (3 * D) + h * 64 + lane]) * 0.125f;  // 1/sqrt(64)
    int jlo = i - (BAND - 1); if (jlo < 0) jlo = 0;

    float m = -3e38f, den = 0.f, acc = 0.f;
    for (int j = jlo; j <= i; ++j) {
        float kv = bf2f(base[(size_t)j * (3 * D) + D + h * 64 + lane]);
        float p = q * kv;
        #pragma unroll
        for (int off = 32; off > 0; off >>= 1) p += __shfl_xor(p, off);
        if (pad[t - i + j]) p -= 1e9f;   // pad[b*512 + j]
        float mn = fmaxf(m, p);
        float sc = __expf(m - mn);
        float w  = __expf(p - mn);
        float vv = bf2f(base[(size_t)j * (3 * D) + 2 * D + h * 64 + lane]);
        den = den * sc + w;
        acc = acc * sc + w * vv;
        m = mn;
    }
    o[(size_t)t * D + h * 64 + lane] = f2bf(acc / den);
}

// ---------------------------------------------------------------------------
// Fused residual + LayerNorm: x = LN(xin + delta) * g + bt; writes fp32 + bf16.
// One wave per row of 512.
// ---------------------------------------------------------------------------
__global__ __launch_bounds__(256) void resln_kernel(
    const float* __restrict__ xin, const float* __restrict__ delta,
    const float* __restrict__ g, const float* __restrict__ bt,
    float* __restrict__ xf, u16* __restrict__ xb)
{
    int row  = blockIdx.x * 4 + (threadIdx.x >> 6);
    int lane = threadIdx.x & 63;
    const float* xr = xin + (size_t)row * D;
    const float* dr = delta + (size_t)row * D;

    float vals[8];
    float s = 0.f, s2 = 0.f;
    #pragma unroll
    for (int tt = 0; tt < 8; ++tt) {
        int c = lane + tt * 64;
        float y = xr[c] + dr[c];
        vals[tt] = y; s += y; s2 += y * y;
    }
    #pragma unroll
    for (int off = 32; off > 0; off >>= 1) {
        s  += __shfl_xor(s, off);
        s2 += __shfl_xor(s2, off);
    }
    float mean = s * (1.f / D);
    float var  = s2 * (1.f / D) - mean * mean;
    float inv  = rsqrtf(fmaxf(var, 0.f) + 1e-5f);
    #pragma unroll
    for (int tt = 0; tt < 8; ++tt) {
        int c = lane + tt * 64;
        float y = (vals[tt] - mean) * inv * g[c] + bt[c];
        xf[(size_t)row * D + c] = y;
        xb[(size_t)row * D + c] = f2bf(y);
    }
}

// ---------------------------------------------------------------------------
// pad[b*512+i] = 1 iff all 300 goal entries == -1 exactly. One wave per row.
// ---------------------------------------------------------------------------
__global__ __launch_bounds__(256) void pad_kernel(
    const float* __restrict__ goal, unsigned char* __restrict__ pad)
{
    int row  = blockIdx.x * 4 + (threadIdx.x >> 6);
    int lane = threadIdx.x & 63;
    bool any = false;
    for (int c = lane; c < 300; c += 64)
        any |= (goal[(size_t)row * 300 + c] != -1.0f);
    unsigned long long b = __ballot(any);
    if (lane == 0) pad[row] = (b == 0ull) ? 1 : 0;
}

// ---------------------------------------------------------------------------
// Batched fp32 -> bf16 (or fp32 copy) conversion. mode 0: flat f32->bf16;
// mode 1: flat f32->f32; mode 2: f32->bf16 with row pad (srcld -> dstld, zeros).
// ---------------------------------------------------------------------------
struct CvtJob { const float* src; u16* dstb; float* dstf; int n; int mode; int srcld; int dstld; };
struct CvtArgs { CvtJob j[14]; };

__global__ __launch_bounds__(256) void cvt_kernel(CvtArgs a) {
    CvtJob jb = a.j[blockIdx.y];
    int i0 = blockIdx.x * 2048 + threadIdx.x;
    if (jb.mode == 2) {
        #pragma unroll
        for (int t = 0; t < 8; ++t) {
            int i = i0 + t * 256;
            if (i < jb.n) {
                int r = i / jb.dstld, c = i - r * jb.dstld;
                jb.dstb[i] = (c < jb.srcld) ? f2bf(jb.src[(size_t)r * jb.srcld + c]) : (u16)0;
            }
        }
    } else if (jb.mode == 1) {
        #pragma unroll
        for (int t = 0; t < 8; ++t) { int i = i0 + t * 256; if (i < jb.n) jb.dstf[i] = jb.src[i]; }
    } else {
        #pragma unroll
        for (int t = 0; t < 8; ++t) { int i = i0 + t * 256; if (i < jb.n) jb.dstb[i] = f2bf(jb.src[i]); }
    }
}

// ---------------------------------------------------------------------------

extern "C" void kernel_launch(void* const* d_in, const int* in_sizes, int n_in,
                              void* d_out, int out_size, void* d_ws, size_t ws_size,
                              hipStream_t stream)
{
    const float* state  = (const float*)d_in[0];   // (16,512,3,16,16) -> 8192x768
    const float* goal   = (const float*)d_in[1];   // 8192x300
    const float* W_obs  = (const float*)d_in[2];   // 256x768
    const float* b_obs  = (const float*)d_in[3];
    const float* W_lang = (const float*)d_in[4];   // 256x300
    const float* b_lang = (const float*)d_in[5];
    const float* W_in   = (const float*)d_in[6];   // 512x512
    const float* b_in   = (const float*)d_in[7];
    const float* Wqkv   = (const float*)d_in[8];   // 3x1536x512
    const float* bqkv   = (const float*)d_in[9];
    const float* Wo     = (const float*)d_in[10];  // 3x512x512
    const float* bo     = (const float*)d_in[11];
    const float* W1     = (const float*)d_in[12];  // 3x2048x512
    const float* b1     = (const float*)d_in[13];
    const float* W2     = (const float*)d_in[14];  // 3x512x2048
    const float* b2     = (const float*)d_in[15];
    const float* g1     = (const float*)d_in[16];
    const float* bt1    = (const float*)d_in[17];
    const float* g2     = (const float*)d_in[18];
    const float* bt2    = (const float*)d_in[19];
    const float* W_outp = (const float*)d_in[20];  // 256x512
    const float* b_outp = (const float*)d_in[21];
    const float* W_a1   = (const float*)d_in[22];  // 12x256
    const float* b_a1   = (const float*)d_in[23];
    const float* W_a2   = (const float*)d_in[24];  // 89x256
    const float* b_a2   = (const float*)d_in[25];

    char* ws = (char*)d_ws;
    size_t off = 0;
    auto alloc = [&](size_t bytes) -> void* {
        void* p = ws + off;
        off = (off + bytes + 255) & ~(size_t)255;
        return p;
    };

    u16* wqkv_b  = (u16*)alloc((size_t)NL * 1536 * D * 2);
    u16* wo_b    = (u16*)alloc((size_t)NL * D * D * 2);
    u16* w1_b    = (u16*)alloc((size_t)NL * FFD * D * 2);
    u16* w2_b    = (u16*)alloc((size_t)NL * D * FFD * 2);
    u16* wobs_b  = (u16*)alloc((size_t)256 * 768 * 2);
    u16* wlang_b = (u16*)alloc((size_t)256 * 320 * 2);
    u16* win_b   = (u16*)alloc((size_t)D * D * 2);
    u16* woutp_b = (u16*)alloc((size_t)HID * D * 2);
    u16* wa_b    = (u16*)alloc((size_t)NOUT * HID * 2);
    float* ba_f  = (float*)alloc((size_t)NOUT * 4);
    u16* state_b = (u16*)alloc((size_t)MTOK * 768 * 2);
    u16* goal_b  = (u16*)alloc((size_t)MTOK * 320 * 2);
    u16* feat_b  = (u16*)alloc((size_t)MTOK * D * 2);
    float* x_f   = (float*)alloc((size_t)MTOK * D * 4);
    u16* x_b     = (u16*)alloc((size_t)MTOK * D * 2);
    u16* qkv_b   = (u16*)alloc((size_t)MTOK * 3 * D * 2);
    u16* o_b     = (u16*)alloc((size_t)MTOK * D * 2);
    float* delta_f = (float*)alloc((size_t)MTOK * D * 4);
    u16* h1_b    = (u16*)alloc((size_t)MTOK * FFD * 2);
    u16* hout_b  = (u16*)alloc((size_t)MTOK * HID * 2);
    unsigned char* pad_u8 = (unsigned char*)alloc(MTOK);
    (void)ws_size; (void)in_sizes; (void)n_in; (void)out_size;

    // ---- conversions (one batched launch) ----
    CvtArgs ca;
    int nj = 0;
    auto addj = [&](const float* s, u16* db, float* df, int n, int mode, int sld, int dld) {
        ca.j[nj].src = s; ca.j[nj].dstb = db; ca.j[nj].dstf = df;
        ca.j[nj].n = n; ca.j[nj].mode = mode; ca.j[nj].srcld = sld; ca.j[nj].dstld = dld;
        ++nj;
    };
    addj(state,  state_b, nullptr, MTOK * 768, 0, 0, 0);
    addj(goal,   goal_b,  nullptr, MTOK * 320, 2, 300, 320);
    addj(Wqkv,   wqkv_b,  nullptr, NL * 1536 * D, 0, 0, 0);
    addj(Wo,     wo_b,    nullptr, NL * D * D, 0, 0, 0);
    addj(W1,     w1_b,    nullptr, NL * FFD * D, 0, 0, 0);
    addj(W2,     w2_b,    nullptr, NL * D * FFD, 0, 0, 0);
    addj(W_obs,  wobs_b,  nullptr, 256 * 768, 0, 0, 0);
    addj(W_lang, wlang_b, nullptr, 256 * 320, 2, 300, 320);
    addj(W_in,   win_b,   nullptr, D * D, 0, 0, 0);
    addj(W_outp, woutp_b, nullptr, HID * D, 0, 0, 0);
    addj(W_a1,   wa_b,            nullptr, 12 * HID, 0, 0, 0);
    addj(W_a2,   wa_b + 12 * HID, nullptr, 89 * HID, 0, 0, 0);
    addj(b_a1,   nullptr, ba_f,      12, 1, 0, 0);
    addj(b_a2,   nullptr, ba_f + 12, 89, 1, 0, 0);
    {
        dim3 grid((MTOK * 768 + 2047) / 2048, 14);
        cvt_kernel<<<grid, 256, 0, stream>>>(ca);
    }

    pad_kernel<<<MTOK / 4, 256, 0, stream>>>(goal, pad_u8);

    auto gemm = [&](const u16* A, int lda, const u16* B, int ldb, const float* bias,
                    float* Cf, int ldcf, u16* Cb, int ldcb, int N, int K, int relu) {
        dim3 grid((N + BN - 1) / BN, MTOK / BM);
        gemm_kernel<<<grid, 256, 0, stream>>>(A, lda, B, ldb, bias, Cf, ldcf, Cb, ldcb,
                                              MTOK, N, K, relu);
    };

    // input projections -> feat (obs cols 0:256, lang cols 256:512)
    gemm(state_b, 768, wobs_b, 768, b_obs, nullptr, 0, feat_b, D, 256, 768, 0);
    gemm(goal_b, 320, wlang_b, 320, b_lang, nullptr, 0, feat_b + 256, D, 256, 320, 0);
    // x = feat @ W_in^T + b_in
    gemm(feat_b, D, win_b, D, b_in, x_f, D, x_b, D, D, D, 0);

    for (int l = 0; l < NL; ++l) {
        gemm(x_b, D, wqkv_b + (size_t)l * 1536 * D, D, bqkv + l * 1536,
             nullptr, 0, qkv_b, 3 * D, 3 * D, D, 0);
        attn_kernel<<<MTOK * H / 4, 256, 0, stream>>>(qkv_b, pad_u8, o_b);
        gemm(o_b, D, wo_b + (size_t)l * D * D, D, bo + l * D,
             delta_f, D, nullptr, 0, D, D, 0);
        resln_kernel<<<MTOK / 4, 256, 0, stream>>>(x_f, delta_f, g1 + l * D, bt1 + l * D, x_f, x_b);
        gemm(x_b, D, w1_b + (size_t)l * FFD * D, D, b1 + l * FFD,
             nullptr, 0, h1_b, FFD, FFD, D, 1);
        gemm(h1_b, FFD, w2_b + (size_t)l * D * FFD, FFD, b2 + l * D,
             delta_f, D, nullptr, 0, D, FFD, 0);
        resln_kernel<<<MTOK / 4, 256, 0, stream>>>(x_f, delta_f, g2 + l * D, bt2 + l * D, x_f, x_b);
    }

    // output head
    gemm(x_b, D, woutp_b, D, b_outp, nullptr, 0, hout_b, HID, HID, D, 0);
    gemm(hout_b, HID, wa_b, HID, ba_f, (float*)d_out, NOUT, nullptr, 0, NOUT, HID, 0);
}

// Round 2
// 601.147 us; speedup vs baseline: 1.5490x; 1.5490x over previous
//
#include <hip/hip_runtime.h>

#define D 512
#define H 8
#define NL 3
#define FFD 2048
#define HID 256
#define BAND 17
#define BATCH 16
#define SEQ 512
#define MTOK (BATCH * SEQ)   // 8192
#define NOUT 101             // 12 + 89
#define NOUTP 128            // NOUT padded to 128 rows

typedef unsigned short u16;
typedef __attribute__((ext_vector_type(8))) short short8;     // bf16x8 MFMA frag
typedef __attribute__((ext_vector_type(4))) float f32x4;
typedef __attribute__((ext_vector_type(8))) unsigned short u16x8;

__device__ inline float bf2f(u16 u) {
    union { unsigned int i; float f; } x; x.i = ((unsigned int)u) << 16; return x.f;
}
__device__ inline u16 f2bf(float f) {
    union { float f; unsigned int i; } x; x.f = f;
    unsigned int r = x.i + 0x7fffu + ((x.i >> 16) & 1u);
    return (u16)(r >> 16);
}

// async global->LDS, 16B per lane; LDS dest = wave-uniform base + lane*16
__device__ __forceinline__ void gload_lds16(const u16* g, u16* l) {
    __builtin_amdgcn_global_load_lds(
        (const __attribute__((address_space(1))) unsigned int*)(g),
        (__attribute__((address_space(3))) unsigned int*)(l),
        16, 0, 0);
}

// ---------------------------------------------------------------------------
// bf16 MFMA GEMM (m97 structure): C(MxN) = A(MxK) @ B(NxK)^T + bias, opt relu.
// Linear LDS tiles + global_load_lds width-16. M mult of 128; N of B buffer
// mult of 128 (zero-padded); K mult of 32. 128x128 tile, BK=32, 4 waves.
// ---------------------------------------------------------------------------
#define BM 128
#define BN 128
#define BK 32

__global__ __launch_bounds__(256) void gemm_kernel(
    const u16* __restrict__ A, int lda,
    const u16* __restrict__ B, int ldb,
    const float* __restrict__ bias,
    float* __restrict__ Cf, int ldcf,
    u16* __restrict__ Cb, int ldcb,
    int M, int N, int K, int relu)
{
    __shared__ u16 As[BM * BK];   // 8 KB, linear rows of 64B
    __shared__ u16 Bs[BN * BK];
    const int tid  = threadIdx.x;
    const int lane = tid & 63;
    const int wv   = tid >> 6;
    const int wr = wv >> 1, wc = wv & 1;
    const int m0 = blockIdx.y * BM, n0 = blockIdx.x * BN;

    f32x4 acc[4][4] = {};

    const int kcol = (lane >> 4) << 3;   // 0,8,16,24
    const int frow = lane & 15;
    const int srow = lane >> 2;          // staging: row within 16-row segment
    const int skg  = (lane & 3) << 3;    // staging: k offset 0,8,16,24

    for (int k0 = 0; k0 < K; k0 += BK) {
        #pragma unroll
        for (int s = 0; s < 2; ++s) {
            int r0 = (wv * 2 + s) * 16;  // 16-row segment = 1KB LDS region
            gload_lds16(A + (size_t)(m0 + r0 + srow) * lda + (k0 + skg), &As[r0 * BK]);
            gload_lds16(B + (size_t)(n0 + r0 + srow) * ldb + (k0 + skg), &Bs[r0 * BK]);
        }
        __syncthreads();

        short8 af[4], bf[4];
        #pragma unroll
        for (int i = 0; i < 4; ++i)
            af[i] = *(const short8*)&As[(wr * 64 + i * 16 + frow) * BK + kcol];
        #pragma unroll
        for (int j = 0; j < 4; ++j)
            bf[j] = *(const short8*)&Bs[(wc * 64 + j * 16 + frow) * BK + kcol];

        #pragma unroll
        for (int i = 0; i < 4; ++i)
            #pragma unroll
            for (int j = 0; j < 4; ++j)
                acc[i][j] = __builtin_amdgcn_mfma_f32_16x16x32_bf16(af[i], bf[j], acc[i][j], 0, 0, 0);
        __syncthreads();
    }

    // C/D layout: col = lane&15, row = (lane>>4)*4 + reg  [m89/m91]
    const int crow0 = (lane >> 4) * 4;
    const int ccol  = lane & 15;
    #pragma unroll
    for (int j = 0; j < 4; ++j) {
        int gcol = n0 + wc * 64 + j * 16 + ccol;
        if (gcol >= N) continue;
        float bv = bias ? bias[gcol] : 0.f;
        #pragma unroll
        for (int i = 0; i < 4; ++i) {
            #pragma unroll
            for (int r = 0; r < 4; ++r) {
                int grow = m0 + wr * 64 + i * 16 + crow0 + r;
                float v = acc[i][j][r] + bv;
                if (relu) v = fmaxf(v, 0.f);
                if (Cf) Cf[(size_t)grow * ldcf + gcol] = v;
                if (Cb) Cb[(size_t)grow * ldcb + gcol] = f2bf(v);
            }
        }
    }
}

// ---------------------------------------------------------------------------
// MFMA banded attention. Block = (b, h, 128-query chunk), 512 threads, 8 waves.
// Wave w handles the 16-query block qb=w. Window = 32 keys [i0-16, i0+16).
// S = Q@K^T via 4 MFMA (Q/K frags direct from global), masked softmax in-reg,
// P staged in per-wave LDS, O = P@V via 4 MFMA with V transposed in LDS.
// ---------------------------------------------------------------------------
#define CHUNK 128
#define KSLOT 144            // CHUNK + 16 key slots
#define VT_LD 152            // Vt row stride in u16 (+8 pad)

__global__ __launch_bounds__(512) void attn_kernel(
    const u16* __restrict__ qkv, const unsigned char* __restrict__ pad,
    u16* __restrict__ o)
{
    __shared__ u16 Vt[64 * VT_LD];        // V^T: [d][key slot], 19456 B
    __shared__ u16 Pl[8 * 16 * 40];       // per-wave P tiles [16][40]
    __shared__ unsigned char padl[KSLOT];

    const int tid = threadIdx.x, lane = tid & 63, wv = tid >> 6;
    const int b = blockIdx.z, h = blockIdx.y, c0 = blockIdx.x * CHUNK;
    const u16* base = qkv + (size_t)b * SEQ * (3 * D);

    // ---- stage V^T (rows j = c0-16+t) + pad flags ----
    for (int s = tid; s < KSLOT * 4; s += 512) {
        int t = s >> 2, dq = (s & 3) * 16;
        int j = c0 - 16 + t; if (j < 0) j = 0;
        const u16* vrow = base + (size_t)j * (3 * D) + 2 * D + h * 64 + dq;
        u16 tmp[16];
        *(u16x8*)&tmp[0] = *(const u16x8*)&vrow[0];
        *(u16x8*)&tmp[8] = *(const u16x8*)&vrow[8];
        #pragma unroll
        for (int d = 0; d < 16; ++d)
            Vt[(dq + d) * VT_LD + t] = tmp[d];
    }
    if (tid < KSLOT) {
        int j = c0 - 16 + tid;
        padl[tid] = (j >= 0) ? pad[b * SEQ + j] : (unsigned char)1;
    }
    __syncthreads();

    const int qi0 = wv * 16;             // local query start of this wave
    const int i0  = c0 + qi0;            // global query start
    const int frow = lane & 15;
    const int g    = lane >> 4;
    const int kg8  = g * 8;
    const int g4   = g * 4;

    // Q frags (A operand): row = lane&15, k = g*8..+8 over d=64 (2 k-steps)
    short8 qf[2];
    #pragma unroll
    for (int kk = 0; kk < 2; ++kk)
        qf[kk] = *(const short8*)&base[(size_t)(i0 + frow) * (3 * D) + h * 64 + kk * 32 + kg8];

    // S = Q @ K^T  (2 key blocks x 2 k-steps)
    f32x4 sacc[2] = {};
    #pragma unroll
    for (int jb = 0; jb < 2; ++jb) {
        int jrow = i0 - 16 + jb * 16 + frow; if (jrow < 0) jrow = 0;
        const u16* kbase = base + (size_t)jrow * (3 * D) + D + h * 64;
        #pragma unroll
        for (int kk = 0; kk < 2; ++kk) {
            short8 kf = *(const short8*)&kbase[kk * 32 + kg8];
            sacc[jb] = __builtin_amdgcn_mfma_f32_16x16x32_bf16(qf[kk], kf, sacc[jb], 0, 0, 0);
        }
    }

    // mask: query-in-block qq = g*4+r, key slot s = jb*16 + frow;
    // valid iff qq <= s <= qq+16 && j >= 0 && !pad[j]   (banned adds -1e9)
    float sv[2][4];
    #pragma unroll
    for (int jb = 0; jb < 2; ++jb) {
        int s = jb * 16 + frow;
        int jg = i0 - 16 + s;
        bool padk = (jg < 0) || padl[qi0 + s];
        #pragma unroll
        for (int r = 0; r < 4; ++r) {
            int qq = g4 + r;
            bool banned = (s < qq) || (s > qq + 16) || padk;
            sv[jb][r] = sacc[jb][r] * 0.125f + (banned ? -1e9f : 0.f);
        }
    }

    // softmax over each query row (16 lanes hold the 32-key row)
    float ex[2][4], rdn[4];
    #pragma unroll
    for (int r = 0; r < 4; ++r) {
        float m = fmaxf(sv[0][r], sv[1][r]);
        #pragma unroll
        for (int off = 1; off < 16; off <<= 1) m = fmaxf(m, __shfl_xor(m, off));
        float e0 = __expf(sv[0][r] - m);
        float e1 = __expf(sv[1][r] - m);
        float dsum = e0 + e1;
        #pragma unroll
        for (int off = 1; off < 16; off <<= 1) dsum += __shfl_xor(dsum, off);
        ex[0][r] = e0; ex[1][r] = e1;
        rdn[r] = 1.f / dsum;
    }

    // P -> LDS (unnormalized), reload as A-frag
    u16* Pw = &Pl[wv * 640];
    #pragma unroll
    for (int jb = 0; jb < 2; ++jb)
        #pragma unroll
        for (int r = 0; r < 4; ++r)
            Pw[(g4 + r) * 40 + jb * 16 + frow] = f2bf(ex[jb][r]);
    short8 pa = *(const short8*)&Pw[frow * 40 + kg8];

    // O = P @ V  (4 d-blocks, K=32 keys in one MFMA each)
    f32x4 oacc[4] = {};
    #pragma unroll
    for (int nb = 0; nb < 4; ++nb) {
        short8 vf = *(const short8*)&Vt[(nb * 16 + frow) * VT_LD + qi0 + kg8];
        oacc[nb] = __builtin_amdgcn_mfma_f32_16x16x32_bf16(pa, vf, oacc[nb], 0, 0, 0);
    }

    // store O: row = query qq = g*4+r, col = d = nb*16 + frow
    #pragma unroll
    for (int r = 0; r < 4; ++r) {
        size_t row = (size_t)(b * SEQ + i0 + g4 + r);
        #pragma unroll
        for (int nb = 0; nb < 4; ++nb)
            o[row * D + h * 64 + nb * 16 + frow] = f2bf(oacc[nb][r] * rdn[r]);
    }
}

// ---------------------------------------------------------------------------
// Fused residual + LayerNorm: x = LN(xin + delta) * g + bt; writes fp32 + bf16.
// ---------------------------------------------------------------------------
__global__ __launch_bounds__(256) void resln_kernel(
    const float* __restrict__ xin, const float* __restrict__ delta,
    const float* __restrict__ g, const float* __restrict__ bt,
    float* __restrict__ xf, u16* __restrict__ xb)
{
    int row  = blockIdx.x * 4 + (threadIdx.x >> 6);
    int lane = threadIdx.x & 63;
    const float* xr = xin + (size_t)row * D;
    const float* dr = delta + (size_t)row * D;

    float vals[8];
    float s = 0.f, s2 = 0.f;
    #pragma unroll
    for (int tt = 0; tt < 8; ++tt) {
        int c = lane + tt * 64;
        float y = xr[c] + dr[c];
        vals[tt] = y; s += y; s2 += y * y;
    }
    #pragma unroll
    for (int off = 32; off > 0; off >>= 1) {
        s  += __shfl_xor(s, off);
        s2 += __shfl_xor(s2, off);
    }
    float mean = s * (1.f / D);
    float var  = s2 * (1.f / D) - mean * mean;
    float inv  = rsqrtf(fmaxf(var, 0.f) + 1e-5f);
    #pragma unroll
    for (int tt = 0; tt < 8; ++tt) {
        int c = lane + tt * 64;
        float y = (vals[tt] - mean) * inv * g[c] + bt[c];
        xf[(size_t)row * D + c] = y;
        xb[(size_t)row * D + c] = f2bf(y);
    }
}

// ---------------------------------------------------------------------------
// pad[b*512+i] = 1 iff all 300 goal entries == -1 exactly. One wave per row.
// ---------------------------------------------------------------------------
__global__ __launch_bounds__(256) void pad_kernel(
    const float* __restrict__ goal, unsigned char* __restrict__ pad)
{
    int row  = blockIdx.x * 4 + (threadIdx.x >> 6);
    int lane = threadIdx.x & 63;
    bool any = false;
    for (int c = lane; c < 300; c += 64)
        any |= (goal[(size_t)row * 300 + c] != -1.0f);
    unsigned long long b = __ballot(any);
    if (lane == 0) pad[row] = (b == 0ull) ? 1 : 0;
}

// ---------------------------------------------------------------------------
// Batched conversions. mode 0: flat f32->bf16; mode 1: flat f32->f32;
// mode 2: f32->bf16 row-padded (srcld->dstld, zero fill); mode 3: bf16 zero.
// ---------------------------------------------------------------------------
struct CvtJob { const float* src; u16* dstb; float* dstf; int n; int mode; int srcld; int dstld; };
struct CvtArgs { CvtJob j[15]; };

__global__ __launch_bounds__(256) void cvt_kernel(CvtArgs a) {
    CvtJob jb = a.j[blockIdx.y];
    int i0 = blockIdx.x * 2048 + threadIdx.x;
    if (jb.mode == 3) {
        #pragma unroll
        for (int t = 0; t < 8; ++t) { int i = i0 + t * 256; if (i < jb.n) jb.dstb[i] = 0; }
    } else if (jb.mode == 2) {
        #pragma unroll
        for (int t = 0; t < 8; ++t) {
            int i = i0 + t * 256;
            if (i < jb.n) {
                int r = i / jb.dstld, c = i - r * jb.dstld;
                jb.dstb[i] = (c < jb.srcld) ? f2bf(jb.src[(size_t)r * jb.srcld + c]) : (u16)0;
            }
        }
    } else if (jb.mode == 1) {
        #pragma unroll
        for (int t = 0; t < 8; ++t) { int i = i0 + t * 256; if (i < jb.n) jb.dstf[i] = jb.src[i]; }
    } else {
        #pragma unroll
        for (int t = 0; t < 8; ++t) { int i = i0 + t * 256; if (i < jb.n) jb.dstb[i] = f2bf(jb.src[i]); }
    }
}

// ---------------------------------------------------------------------------

extern "C" void kernel_launch(void* const* d_in, const int* in_sizes, int n_in,
                              void* d_out, int out_size, void* d_ws, size_t ws_size,
                              hipStream_t stream)
{
    const float* state  = (const float*)d_in[0];
    const float* goal   = (const float*)d_in[1];
    const float* W_obs  = (const float*)d_in[2];
    const float* b_obs  = (const float*)d_in[3];
    const float* W_lang = (const float*)d_in[4];
    const float* b_lang = (const float*)d_in[5];
    const float* W_in   = (const float*)d_in[6];
    const float* b_in   = (const float*)d_in[7];
    const float* Wqkv   = (const float*)d_in[8];
    const float* bqkv   = (const float*)d_in[9];
    const float* Wo     = (const float*)d_in[10];
    const float* bo     = (const float*)d_in[11];
    const float* W1     = (const float*)d_in[12];
    const float* b1     = (const float*)d_in[13];
    const float* W2     = (const float*)d_in[14];
    const float* b2     = (const float*)d_in[15];
    const float* g1     = (const float*)d_in[16];
    const float* bt1    = (const float*)d_in[17];
    const float* g2     = (const float*)d_in[18];
    const float* bt2    = (const float*)d_in[19];
    const float* W_outp = (const float*)d_in[20];
    const float* b_outp = (const float*)d_in[21];
    const float* W_a1   = (const float*)d_in[22];
    const float* b_a1   = (const float*)d_in[23];
    const float* W_a2   = (const float*)d_in[24];
    const float* b_a2   = (const float*)d_in[25];

    char* ws = (char*)d_ws;
    size_t off = 0;
    auto alloc = [&](size_t bytes) -> void* {
        void* p = ws + off;
        off = (off + bytes + 255) & ~(size_t)255;
        return p;
    };

    u16* wqkv_b  = (u16*)alloc((size_t)NL * 1536 * D * 2);
    u16* wo_b    = (u16*)alloc((size_t)NL * D * D * 2);
    u16* w1_b    = (u16*)alloc((size_t)NL * FFD * D * 2);
    u16* w2_b    = (u16*)alloc((size_t)NL * D * FFD * 2);
    u16* wobs_b  = (u16*)alloc((size_t)256 * 768 * 2);
    u16* wlang_b = (u16*)alloc((size_t)256 * 320 * 2);
    u16* win_b   = (u16*)alloc((size_t)D * D * 2);
    u16* woutp_b = (u16*)alloc((size_t)HID * D * 2);
    u16* wa_b    = (u16*)alloc((size_t)NOUTP * HID * 2);   // padded to 128 rows
    float* ba_f  = (float*)alloc((size_t)NOUT * 4);
    u16* state_b = (u16*)alloc((size_t)MTOK * 768 * 2);
    u16* goal_b  = (u16*)alloc((size_t)MTOK * 320 * 2);
    u16* feat_b  = (u16*)alloc((size_t)MTOK * D * 2);
    float* x_f   = (float*)alloc((size_t)MTOK * D * 4);
    u16* x_b     = (u16*)alloc((size_t)MTOK * D * 2);
    u16* qkv_b   = (u16*)alloc((size_t)MTOK * 3 * D * 2);
    u16* o_b     = (u16*)alloc((size_t)MTOK * D * 2);
    float* delta_f = (float*)alloc((size_t)MTOK * D * 4);
    u16* h1_b    = (u16*)alloc((size_t)MTOK * FFD * 2);
    u16* hout_b  = (u16*)alloc((size_t)MTOK * HID * 2);
    unsigned char* pad_u8 = (unsigned char*)alloc(MTOK);
    (void)ws_size; (void)in_sizes; (void)n_in; (void)out_size;

    // ---- conversions (one batched launch) ----
    CvtArgs ca;
    int nj = 0;
    auto addj = [&](const float* s, u16* db, float* df, int n, int mode, int sld, int dld) {
        ca.j[nj].src = s; ca.j[nj].dstb = db; ca.j[nj].dstf = df;
        ca.j[nj].n = n; ca.j[nj].mode = mode; ca.j[nj].srcld = sld; ca.j[nj].dstld = dld;
        ++nj;
    };
    addj(state,  state_b, nullptr, MTOK * 768, 0, 0, 0);
    addj(goal,   goal_b,  nullptr, MTOK * 320, 2, 300, 320);
    addj(Wqkv,   wqkv_b,  nullptr, NL * 1536 * D, 0, 0, 0);
    addj(Wo,     wo_b,    nullptr, NL * D * D, 0, 0, 0);
    addj(W1,     w1_b,    nullptr, NL * FFD * D, 0, 0, 0);
    addj(W2,     w2_b,    nullptr, NL * D * FFD, 0, 0, 0);
    addj(W_obs,  wobs_b,  nullptr, 256 * 768, 0, 0, 0);
    addj(W_lang, wlang_b, nullptr, 256 * 320, 2, 300, 320);
    addj(W_in,   win_b,   nullptr, D * D, 0, 0, 0);
    addj(W_outp, woutp_b, nullptr, HID * D, 0, 0, 0);
    addj(W_a1,   wa_b,            nullptr, 12 * HID, 0, 0, 0);
    addj(W_a2,   wa_b + 12 * HID, nullptr, 89 * HID, 0, 0, 0);
    addj(nullptr, wa_b + NOUT * HID, nullptr, (NOUTP - NOUT) * HID, 3, 0, 0);  // zero pad rows
    addj(b_a1,   nullptr, ba_f,      12, 1, 0, 0);
    addj(b_a2,   nullptr, ba_f + 12, 89, 1, 0, 0);
    {
        dim3 grid((MTOK * 768 + 2047) / 2048, 15);
        cvt_kernel<<<grid, 256, 0, stream>>>(ca);
    }

    pad_kernel<<<MTOK / 4, 256, 0, stream>>>(goal, pad_u8);

    auto gemm = [&](const u16* A, int lda, const u16* B, int ldb, const float* bias,
                    float* Cf, int ldcf, u16* Cb, int ldcb, int N, int K, int relu) {
        dim3 grid((N + BN - 1) / BN, MTOK / BM);
        gemm_kernel<<<grid, 256, 0, stream>>>(A, lda, B, ldb, bias, Cf, ldcf, Cb, ldcb,
                                              MTOK, N, K, relu);
    };

    // input projections -> feat (obs cols 0:256, lang cols 256:512)
    gemm(state_b, 768, wobs_b, 768, b_obs, nullptr, 0, feat_b, D, 256, 768, 0);
    gemm(goal_b, 320, wlang_b, 320, b_lang, nullptr, 0, feat_b + 256, D, 256, 320, 0);
    gemm(feat_b, D, win_b, D, b_in, x_f, D, x_b, D, D, D, 0);

    for (int l = 0; l < NL; ++l) {
        gemm(x_b, D, wqkv_b + (size_t)l * 1536 * D, D, bqkv + l * 1536,
             nullptr, 0, qkv_b, 3 * D, 3 * D, D, 0);
        {
            dim3 grid(SEQ / CHUNK, H, BATCH);
            attn_kernel<<<grid, 512, 0, stream>>>(qkv_b, pad_u8, o_b);
        }
        gemm(o_b, D, wo_b + (size_t)l * D * D, D, bo + l * D,
             delta_f, D, nullptr, 0, D, D, 0);
        resln_kernel<<<MTOK / 4, 256, 0, stream>>>(x_f, delta_f, g1 + l * D, bt1 + l * D, x_f, x_b);
        gemm(x_b, D, w1_b + (size_t)l * FFD * D, D, b1 + l * FFD,
             nullptr, 0, h1_b, FFD, FFD, D, 1);
        gemm(h1_b, FFD, w2_b + (size_t)l * D * FFD, FFD, b2 + l * D,
             delta_f, D, nullptr, 0, D, FFD, 0);
        resln_kernel<<<MTOK / 4, 256, 0, stream>>>(x_f, delta_f, g2 + l * D, bt2 + l * D, x_f, x_b);
    }

    // output head
    gemm(x_b, D, woutp_b, D, b_outp, nullptr, 0, hout_b, HID, HID, D, 0);
    gemm(hout_b, HID, wa_b, HID, ba_f, (float*)d_out, NOUT, nullptr, 0, NOUT, HID, 0);
}

// Round 3
// 556.434 us; speedup vs baseline: 1.6734x; 1.0804x over previous
//
#include <hip/hip_runtime.h>

#define D 512
#define H 8
#define NL 3
#define FFD 2048
#define HID 256
#define BAND 17
#define BATCH 16
#define SEQ 512
#define MTOK (BATCH * SEQ)   // 8192
#define NOUT 101             // 12 + 89
#define NOUTP 128            // NOUT padded to 128 rows

typedef unsigned short u16;
typedef __attribute__((ext_vector_type(8))) short short8;     // bf16x8 MFMA frag
typedef __attribute__((ext_vector_type(4))) float f32x4;
typedef __attribute__((ext_vector_type(8))) unsigned short u16x8;

__device__ inline float bf2f(u16 u) {
    union { unsigned int i; float f; } x; x.i = ((unsigned int)u) << 16; return x.f;
}
__device__ inline u16 f2bf(float f) {
    union { float f; unsigned int i; } x; x.f = f;
    unsigned int r = x.i + 0x7fffu + ((x.i >> 16) & 1u);
    return (u16)(r >> 16);
}

// async global->LDS, 16B per lane; LDS dest = wave-uniform base + lane*16
__device__ __forceinline__ void gload_lds16(const u16* g, u16* l) {
    __builtin_amdgcn_global_load_lds(
        (const __attribute__((address_space(1))) unsigned int*)(g),
        (__attribute__((address_space(3))) unsigned int*)(l),
        16, 0, 0);
}

// ---------------------------------------------------------------------------
// bf16 MFMA GEMM (m97 structure): C = A(MxK) @ B(NxK)^T + bias, opt relu.
// Linear LDS + global_load_lds w16. Split-K via blockIdx.z (0 -> Cf0, 1 -> Cf1;
// bias applied by z==0 only). Bijective XCD swizzle on the (x,y) block id
// (requires gridX*gridY % 8 == 0 -- guaranteed by launcher).
// ---------------------------------------------------------------------------
#define BM 128
#define BN 128
#define BK 32

__global__ __launch_bounds__(256) void gemm_kernel(
    const u16* __restrict__ A, int lda,
    const u16* __restrict__ B, int ldb,
    const float* __restrict__ bias,
    float* __restrict__ Cf0, float* __restrict__ Cf1, int ldcf,
    u16* __restrict__ Cb, int ldcb,
    int M, int N, int K, int relu)
{
    __shared__ u16 As[BM * BK];   // 8 KB, linear rows of 64B
    __shared__ u16 Bs[BN * BK];
    const int tid  = threadIdx.x;
    const int lane = tid & 63;
    const int wv   = tid >> 6;
    const int wr = wv >> 1, wc = wv & 1;

    // XCD-aware bijective swizzle (nb % 8 == 0)
    const int nb  = gridDim.x * gridDim.y;
    const int bid = blockIdx.y * gridDim.x + blockIdx.x;
    const int tile = (bid & 7) * (nb >> 3) + (bid >> 3);
    const int m0 = (tile / gridDim.x) * BM;
    const int n0 = (tile % gridDim.x) * BN;
    const int kz = blockIdx.z * K;

    f32x4 acc[4][4] = {};

    const int kcol = (lane >> 4) << 3;   // 0,8,16,24
    const int frow = lane & 15;
    const int srow = lane >> 2;          // staging: row within 16-row segment
    const int skg  = (lane & 3) << 3;    // staging: k offset 0,8,16,24

    for (int k0 = 0; k0 < K; k0 += BK) {
        #pragma unroll
        for (int s = 0; s < 2; ++s) {
            int r0 = (wv * 2 + s) * 16;  // 16-row segment = 1KB LDS region
            gload_lds16(A + (size_t)(m0 + r0 + srow) * lda + (kz + k0 + skg), &As[r0 * BK]);
            gload_lds16(B + (size_t)(n0 + r0 + srow) * ldb + (kz + k0 + skg), &Bs[r0 * BK]);
        }
        __syncthreads();

        short8 af[4], bf[4];
        #pragma unroll
        for (int i = 0; i < 4; ++i)
            af[i] = *(const short8*)&As[(wr * 64 + i * 16 + frow) * BK + kcol];
        #pragma unroll
        for (int j = 0; j < 4; ++j)
            bf[j] = *(const short8*)&Bs[(wc * 64 + j * 16 + frow) * BK + kcol];

        #pragma unroll
        for (int i = 0; i < 4; ++i)
            #pragma unroll
            for (int j = 0; j < 4; ++j)
                acc[i][j] = __builtin_amdgcn_mfma_f32_16x16x32_bf16(af[i], bf[j], acc[i][j], 0, 0, 0);
        __syncthreads();
    }

    float* Cf = blockIdx.z ? Cf1 : Cf0;
    const bool addb = (bias != nullptr) && (blockIdx.z == 0);

    // C/D layout: col = lane&15, row = (lane>>4)*4 + reg  [m89/m91]
    const int crow0 = (lane >> 4) * 4;
    const int ccol  = lane & 15;
    #pragma unroll
    for (int j = 0; j < 4; ++j) {
        int gcol = n0 + wc * 64 + j * 16 + ccol;
        if (gcol >= N) continue;
        float bv = addb ? bias[gcol] : 0.f;
        #pragma unroll
        for (int i = 0; i < 4; ++i) {
            #pragma unroll
            for (int r = 0; r < 4; ++r) {
                int grow = m0 + wr * 64 + i * 16 + crow0 + r;
                float v = acc[i][j][r] + bv;
                if (relu) v = fmaxf(v, 0.f);
                if (Cf) Cf[(size_t)grow * ldcf + gcol] = v;
                if (Cb) Cb[(size_t)grow * ldcb + gcol] = f2bf(v);
            }
        }
    }
}

// ---------------------------------------------------------------------------
// MFMA banded attention. Block = (b, h, 128-query chunk), 512 threads, 8 waves.
// ---------------------------------------------------------------------------
#define CHUNK 128
#define KSLOT 144            // CHUNK + 16 key slots
#define VT_LD 152            // Vt row stride in u16 (+8 pad)

__global__ __launch_bounds__(512) void attn_kernel(
    const u16* __restrict__ qkv, const unsigned char* __restrict__ pad,
    u16* __restrict__ o)
{
    __shared__ u16 Vt[64 * VT_LD];        // V^T: [d][key slot]
    __shared__ u16 Pl[8 * 16 * 40];       // per-wave P tiles [16][40]
    __shared__ unsigned char padl[KSLOT];

    const int tid = threadIdx.x, lane = tid & 63, wv = tid >> 6;
    const int b = blockIdx.z, h = blockIdx.y, c0 = blockIdx.x * CHUNK;
    const u16* base = qkv + (size_t)b * SEQ * (3 * D);

    for (int s = tid; s < KSLOT * 4; s += 512) {
        int t = s >> 2, dq = (s & 3) * 16;
        int j = c0 - 16 + t; if (j < 0) j = 0;
        const u16* vrow = base + (size_t)j * (3 * D) + 2 * D + h * 64 + dq;
        u16 tmp[16];
        *(u16x8*)&tmp[0] = *(const u16x8*)&vrow[0];
        *(u16x8*)&tmp[8] = *(const u16x8*)&vrow[8];
        #pragma unroll
        for (int d = 0; d < 16; ++d)
            Vt[(dq + d) * VT_LD + t] = tmp[d];
    }
    if (tid < KSLOT) {
        int j = c0 - 16 + tid;
        padl[tid] = (j >= 0) ? pad[b * SEQ + j] : (unsigned char)1;
    }
    __syncthreads();

    const int qi0 = wv * 16;
    const int i0  = c0 + qi0;
    const int frow = lane & 15;
    const int g    = lane >> 4;
    const int kg8  = g * 8;
    const int g4   = g * 4;

    short8 qf[2];
    #pragma unroll
    for (int kk = 0; kk < 2; ++kk)
        qf[kk] = *(const short8*)&base[(size_t)(i0 + frow) * (3 * D) + h * 64 + kk * 32 + kg8];

    f32x4 sacc[2] = {};
    #pragma unroll
    for (int jb = 0; jb < 2; ++jb) {
        int jrow = i0 - 16 + jb * 16 + frow; if (jrow < 0) jrow = 0;
        const u16* kbase = base + (size_t)jrow * (3 * D) + D + h * 64;
        #pragma unroll
        for (int kk = 0; kk < 2; ++kk) {
            short8 kf = *(const short8*)&kbase[kk * 32 + kg8];
            sacc[jb] = __builtin_amdgcn_mfma_f32_16x16x32_bf16(qf[kk], kf, sacc[jb], 0, 0, 0);
        }
    }

    float sv[2][4];
    #pragma unroll
    for (int jb = 0; jb < 2; ++jb) {
        int s = jb * 16 + frow;
        int jg = i0 - 16 + s;
        bool padk = (jg < 0) || padl[qi0 + s];
        #pragma unroll
        for (int r = 0; r < 4; ++r) {
            int qq = g4 + r;
            bool banned = (s < qq) || (s > qq + 16) || padk;
            sv[jb][r] = sacc[jb][r] * 0.125f + (banned ? -1e9f : 0.f);
        }
    }

    float ex[2][4], rdn[4];
    #pragma unroll
    for (int r = 0; r < 4; ++r) {
        float m = fmaxf(sv[0][r], sv[1][r]);
        #pragma unroll
        for (int off = 1; off < 16; off <<= 1) m = fmaxf(m, __shfl_xor(m, off));
        float e0 = __expf(sv[0][r] - m);
        float e1 = __expf(sv[1][r] - m);
        float dsum = e0 + e1;
        #pragma unroll
        for (int off = 1; off < 16; off <<= 1) dsum += __shfl_xor(dsum, off);
        ex[0][r] = e0; ex[1][r] = e1;
        rdn[r] = 1.f / dsum;
    }

    u16* Pw = &Pl[wv * 640];
    #pragma unroll
    for (int jb = 0; jb < 2; ++jb)
        #pragma unroll
        for (int r = 0; r < 4; ++r)
            Pw[(g4 + r) * 40 + jb * 16 + frow] = f2bf(ex[jb][r]);
    short8 pa = *(const short8*)&Pw[frow * 40 + kg8];

    f32x4 oacc[4] = {};
    #pragma unroll
    for (int nb = 0; nb < 4; ++nb) {
        short8 vf = *(const short8*)&Vt[(nb * 16 + frow) * VT_LD + qi0 + kg8];
        oacc[nb] = __builtin_amdgcn_mfma_f32_16x16x32_bf16(pa, vf, oacc[nb], 0, 0, 0);
    }

    #pragma unroll
    for (int r = 0; r < 4; ++r) {
        size_t row = (size_t)(b * SEQ + i0 + g4 + r);
        #pragma unroll
        for (int nb = 0; nb < 4; ++nb)
            o[row * D + h * 64 + nb * 16 + frow] = f2bf(oacc[nb][r] * rdn[r]);
    }
}

// ---------------------------------------------------------------------------
// Fused residual + LayerNorm: x = LN(xin + d0 [+ d1]) * g + bt; fp32 + bf16 out.
// ---------------------------------------------------------------------------
__global__ __launch_bounds__(256) void resln_kernel(
    const float* __restrict__ xin,
    const float* __restrict__ d0, const float* __restrict__ d1,
    const float* __restrict__ g, const float* __restrict__ bt,
    float* __restrict__ xf, u16* __restrict__ xb)
{
    int row  = blockIdx.x * 4 + (threadIdx.x >> 6);
    int lane = threadIdx.x & 63;
    const float* xr = xin + (size_t)row * D;
    const float* r0 = d0 + (size_t)row * D;
    const float* r1 = d1 ? d1 + (size_t)row * D : nullptr;

    float vals[8];
    float s = 0.f, s2 = 0.f;
    #pragma unroll
    for (int tt = 0; tt < 8; ++tt) {
        int c = lane + tt * 64;
        float y = xr[c] + r0[c];
        if (r1) y += r1[c];
        vals[tt] = y; s += y; s2 += y * y;
    }
    #pragma unroll
    for (int off = 32; off > 0; off >>= 1) {
        s  += __shfl_xor(s, off);
        s2 += __shfl_xor(s2, off);
    }
    float mean = s * (1.f / D);
    float var  = s2 * (1.f / D) - mean * mean;
    float inv  = rsqrtf(fmaxf(var, 0.f) + 1e-5f);
    #pragma unroll
    for (int tt = 0; tt < 8; ++tt) {
        int c = lane + tt * 64;
        float y = (vals[tt] - mean) * inv * g[c] + bt[c];
        xf[(size_t)row * D + c] = y;
        xb[(size_t)row * D + c] = f2bf(y);
    }
}

// ---------------------------------------------------------------------------
__global__ __launch_bounds__(256) void pad_kernel(
    const float* __restrict__ goal, unsigned char* __restrict__ pad)
{
    int row  = blockIdx.x * 4 + (threadIdx.x >> 6);
    int lane = threadIdx.x & 63;
    bool any = false;
    for (int c = lane; c < 300; c += 64)
        any |= (goal[(size_t)row * 300 + c] != -1.0f);
    unsigned long long b = __ballot(any);
    if (lane == 0) pad[row] = (b == 0ull) ? 1 : 0;
}

// ---------------------------------------------------------------------------
// Batched conversions. mode 0: flat f32->bf16; mode 1: flat f32->f32;
// mode 2: f32->bf16 row-padded (srcld->dstld, zero fill); mode 3: bf16 zero.
// ---------------------------------------------------------------------------
struct CvtJob { const float* src; u16* dstb; float* dstf; int n; int mode; int srcld; int dstld; };
struct CvtArgs { CvtJob j[15]; };

__global__ __launch_bounds__(256) void cvt_kernel(CvtArgs a) {
    CvtJob jb = a.j[blockIdx.y];
    int i0 = blockIdx.x * 2048 + threadIdx.x;
    if (jb.mode == 3) {
        #pragma unroll
        for (int t = 0; t < 8; ++t) { int i = i0 + t * 256; if (i < jb.n) jb.dstb[i] = 0; }
    } else if (jb.mode == 2) {
        #pragma unroll
        for (int t = 0; t < 8; ++t) {
            int i = i0 + t * 256;
            if (i < jb.n) {
                int r = i / jb.dstld, c = i - r * jb.dstld;
                jb.dstb[i] = (c < jb.srcld) ? f2bf(jb.src[(size_t)r * jb.srcld + c]) : (u16)0;
            }
        }
    } else if (jb.mode == 1) {
        #pragma unroll
        for (int t = 0; t < 8; ++t) { int i = i0 + t * 256; if (i < jb.n) jb.dstf[i] = jb.src[i]; }
    } else {
        #pragma unroll
        for (int t = 0; t < 8; ++t) { int i = i0 + t * 256; if (i < jb.n) jb.dstb[i] = f2bf(jb.src[i]); }
    }
}

// ---------------------------------------------------------------------------

extern "C" void kernel_launch(void* const* d_in, const int* in_sizes, int n_in,
                              void* d_out, int out_size, void* d_ws, size_t ws_size,
                              hipStream_t stream)
{
    const float* state  = (const float*)d_in[0];
    const float* goal   = (const float*)d_in[1];
    const float* W_obs  = (const float*)d_in[2];
    const float* b_obs  = (const float*)d_in[3];
    const float* W_lang = (const float*)d_in[4];
    const float* b_lang = (const float*)d_in[5];
    const float* W_in   = (const float*)d_in[6];
    const float* b_in   = (const float*)d_in[7];
    const float* Wqkv   = (const float*)d_in[8];
    const float* bqkv   = (const float*)d_in[9];
    const float* Wo     = (const float*)d_in[10];
    const float* bo     = (const float*)d_in[11];
    const float* W1     = (const float*)d_in[12];
    const float* b1     = (const float*)d_in[13];
    const float* W2     = (const float*)d_in[14];
    const float* b2     = (const float*)d_in[15];
    const float* g1     = (const float*)d_in[16];
    const float* bt1    = (const float*)d_in[17];
    const float* g2     = (const float*)d_in[18];
    const float* bt2    = (const float*)d_in[19];
    const float* W_outp = (const float*)d_in[20];
    const float* b_outp = (const float*)d_in[21];
    const float* W_a1   = (const float*)d_in[22];
    const float* b_a1   = (const float*)d_in[23];
    const float* W_a2   = (const float*)d_in[24];
    const float* b_a2   = (const float*)d_in[25];

    char* ws = (char*)d_ws;
    size_t off = 0;
    auto alloc = [&](size_t bytes) -> void* {
        void* p = ws + off;
        off = (off + bytes + 255) & ~(size_t)255;
        return p;
    };

    u16* wqkv_b  = (u16*)alloc((size_t)NL * 1536 * D * 2);
    u16* wo_b    = (u16*)alloc((size_t)NL * D * D * 2);
    u16* w1_b    = (u16*)alloc((size_t)NL * FFD * D * 2);
    u16* w2_b    = (u16*)alloc((size_t)NL * D * FFD * 2);
    u16* wobs_b  = (u16*)alloc((size_t)256 * 768 * 2);
    u16* wlang_b = (u16*)alloc((size_t)256 * 320 * 2);
    u16* win_b   = (u16*)alloc((size_t)D * D * 2);
    u16* woutp_b = (u16*)alloc((size_t)HID * D * 2);
    u16* wa_b    = (u16*)alloc((size_t)NOUTP * HID * 2);   // padded to 128 rows
    float* ba_f  = (float*)alloc((size_t)NOUT * 4);
    u16* state_b = (u16*)alloc((size_t)MTOK * 768 * 2);    // 12.6 MB \ after input
    u16* goal_b  = (u16*)alloc((size_t)MTOK * 320 * 2);    //  5.2 MB / stage: dead
    u16* feat_b  = (u16*)alloc((size_t)MTOK * D * 2);
    float* x_f   = (float*)alloc((size_t)MTOK * D * 4);
    u16* x_b     = (u16*)alloc((size_t)MTOK * D * 2);
    u16* qkv_b   = (u16*)alloc((size_t)MTOK * 3 * D * 2);
    u16* o_b     = (u16*)alloc((size_t)MTOK * D * 2);
    float* delta_f = (float*)alloc((size_t)MTOK * D * 4);
    u16* h1_b    = (u16*)alloc((size_t)MTOK * FFD * 2);
    u16* hout_b  = (u16*)alloc((size_t)MTOK * HID * 2);
    unsigned char* pad_u8 = (unsigned char*)alloc(MTOK);
    // second split-K partial aliases the dead state_b/goal_b region (17.8 MB >= 16.8 MB)
    float* delta2_f = (float*)state_b;
    (void)ws_size; (void)in_sizes; (void)n_in; (void)out_size;

    // ---- conversions (one batched launch) ----
    CvtArgs ca;
    int nj = 0;
    auto addj = [&](const float* s, u16* db, float* df, int n, int mode, int sld, int dld) {
        ca.j[nj].src = s; ca.j[nj].dstb = db; ca.j[nj].dstf = df;
        ca.j[nj].n = n; ca.j[nj].mode = mode; ca.j[nj].srcld = sld; ca.j[nj].dstld = dld;
        ++nj;
    };
    addj(state,  state_b, nullptr, MTOK * 768, 0, 0, 0);
    addj(goal,   goal_b,  nullptr, MTOK * 320, 2, 300, 320);
    addj(Wqkv,   wqkv_b,  nullptr, NL * 1536 * D, 0, 0, 0);
    addj(Wo,     wo_b,    nullptr, NL * D * D, 0, 0, 0);
    addj(W1,     w1_b,    nullptr, NL * FFD * D, 0, 0, 0);
    addj(W2,     w2_b,    nullptr, NL * D * FFD, 0, 0, 0);
    addj(W_obs,  wobs_b,  nullptr, 256 * 768, 0, 0, 0);
    addj(W_lang, wlang_b, nullptr, 256 * 320, 2, 300, 320);
    addj(W_in,   win_b,   nullptr, D * D, 0, 0, 0);
    addj(W_outp, woutp_b, nullptr, HID * D, 0, 0, 0);
    addj(W_a1,   wa_b,            nullptr, 12 * HID, 0, 0, 0);
    addj(W_a2,   wa_b + 12 * HID, nullptr, 89 * HID, 0, 0, 0);
    addj(nullptr, wa_b + NOUT * HID, nullptr, (NOUTP - NOUT) * HID, 3, 0, 0);
    addj(b_a1,   nullptr, ba_f,      12, 1, 0, 0);
    addj(b_a2,   nullptr, ba_f + 12, 89, 1, 0, 0);
    {
        dim3 grid((MTOK * 768 + 2047) / 2048, 15);
        cvt_kernel<<<grid, 256, 0, stream>>>(ca);
    }

    pad_kernel<<<MTOK / 4, 256, 0, stream>>>(goal, pad_u8);

    // ksplit: 1 = normal; 2 = split-K halves into (Cf0, Cf1), bias in chunk 0
    auto gemm = [&](const u16* A, int lda, const u16* B, int ldb, const float* bias,
                    float* Cf0, float* Cf1, int ldcf, u16* Cb, int ldcb,
                    int N, int K, int relu, int ksplit) {
        dim3 grid((N + BN - 1) / BN, MTOK / BM, ksplit);
        gemm_kernel<<<grid, 256, 0, stream>>>(A, lda, B, ldb, bias, Cf0, Cf1, ldcf,
                                              Cb, ldcb, MTOK, N, K / ksplit, relu);
    };

    // input projections -> feat (obs cols 0:256, lang cols 256:512)
    gemm(state_b, 768, wobs_b, 768, b_obs, nullptr, nullptr, 0, feat_b, D, 256, 768, 0, 1);
    gemm(goal_b, 320, wlang_b, 320, b_lang, nullptr, nullptr, 0, feat_b + 256, D, 256, 320, 0, 1);
    gemm(feat_b, D, win_b, D, b_in, x_f, nullptr, D, x_b, D, D, D, 0, 1);

    for (int l = 0; l < NL; ++l) {
        gemm(x_b, D, wqkv_b + (size_t)l * 1536 * D, D, bqkv + l * 1536,
             nullptr, nullptr, 0, qkv_b, 3 * D, 3 * D, D, 0, 1);
        {
            dim3 grid(SEQ / CHUNK, H, BATCH);
            attn_kernel<<<grid, 512, 0, stream>>>(qkv_b, pad_u8, o_b);
        }
        gemm(o_b, D, wo_b + (size_t)l * D * D, D, bo + l * D,
             delta_f, delta2_f, D, nullptr, 0, D, D, 0, 2);
        resln_kernel<<<MTOK / 4, 256, 0, stream>>>(x_f, delta_f, delta2_f,
                                                   g1 + l * D, bt1 + l * D, x_f, x_b);
        gemm(x_b, D, w1_b + (size_t)l * FFD * D, D, b1 + l * FFD,
             nullptr, nullptr, 0, h1_b, FFD, FFD, D, 1, 1);
        gemm(h1_b, FFD, w2_b + (size_t)l * D * FFD, FFD, b2 + l * D,
             delta_f, delta2_f, D, nullptr, 0, D, FFD, 0, 2);
        resln_kernel<<<MTOK / 4, 256, 0, stream>>>(x_f, delta_f, delta2_f,
                                                   g2 + l * D, bt2 + l * D, x_f, x_b);
    }

    // output head
    gemm(x_b, D, woutp_b, D, b_outp, nullptr, nullptr, 0, hout_b, HID, HID, D, 0, 1);
    gemm(hout_b, HID, wa_b, HID, ba_f, (float*)d_out, nullptr, NOUT, nullptr, 0, NOUT, HID, 0, 1);
}

// Round 4
// 468.022 us; speedup vs baseline: 1.9896x; 1.1889x over previous
//
#include <hip/hip_runtime.h>

#define D 512
#define H 8
#define NL 3
#define FFD 2048
#define HID 256
#define BAND 17
#define BATCH 16
#define SEQ 512
#define MTOK (BATCH * SEQ)   // 8192
#define NOUT 101             // 12 + 89
#define NOUTP 128            // NOUT padded to 128 rows

typedef unsigned short u16;
typedef __attribute__((ext_vector_type(8))) short short8;     // bf16x8 MFMA frag
typedef __attribute__((ext_vector_type(4))) float f32x4;
typedef __attribute__((ext_vector_type(8))) unsigned short u16x8;

__device__ inline float bf2f(u16 u) {
    union { unsigned int i; float f; } x; x.i = ((unsigned int)u) << 16; return x.f;
}
__device__ inline u16 f2bf(float f) {
    union { float f; unsigned int i; } x; x.f = f;
    unsigned int r = x.i + 0x7fffu + ((x.i >> 16) & 1u);
    return (u16)(r >> 16);
}

// async global->LDS, 16B per lane; LDS dest = wave-uniform base + lane*16
__device__ __forceinline__ void gload_lds16(const u16* g, u16* l) {
    __builtin_amdgcn_global_load_lds(
        (const __attribute__((address_space(1))) unsigned int*)(g),
        (__attribute__((address_space(3))) unsigned int*)(l),
        16, 0, 0);
}

// ---------------------------------------------------------------------------
// bf16 MFMA GEMM, 512 threads / 8 waves, 128x128 tile, BK=32.
// Double-buffered LDS + counted vmcnt(2) prefetch (never drain to 0 in loop).
// LDS 16B-chunk XOR swizzle (chunk ^= row&3) applied on BOTH sides: the
// global staging source is pre-swizzled (gload_lds writes LDS linearly) and
// the ds_read address applies the same XOR (rule #21).
// Split-K via blockIdx.z (z=0 -> Cf0 +bias, z=1 -> Cf1). Bijective XCD
// swizzle on (x,y) block id; gridX*gridY % 8 == 0 guaranteed by launcher.
// B buffer must have >= ceil(N/128)*128 rows (zero-padded).
// ---------------------------------------------------------------------------
#define BM 128
#define BN 128
#define BK 32

__global__ __launch_bounds__(512) void gemm_kernel(
    const u16* __restrict__ A, int lda,
    const u16* __restrict__ B, int ldb,
    const float* __restrict__ bias,
    float* __restrict__ Cf0, float* __restrict__ Cf1, int ldcf,
    u16* __restrict__ Cb, int ldcb,
    int M, int N, int K, int relu)
{
    __shared__ u16 As[2][BM * BK];   // 2 x 8 KB
    __shared__ u16 Bs[2][BN * BK];
    const int tid  = threadIdx.x;
    const int lane = tid & 63;
    const int wv   = tid >> 6;          // 0..7
    const int wr = wv >> 2, wc = wv & 3; // wave tile: 64 rows x 32 cols

    // XCD-aware bijective swizzle (nb % 8 == 0)
    const int nb  = gridDim.x * gridDim.y;
    const int bid = blockIdx.y * gridDim.x + blockIdx.x;
    const int tile = (bid & 7) * (nb >> 3) + (bid >> 3);
    const int m0 = (tile / gridDim.x) * BM;
    const int n0 = (tile % gridDim.x) * BN;
    const int kz = blockIdx.z * K;

    f32x4 acc[4][2] = {};

    // staging: thread stages one 16B chunk of A and of B per tile.
    // wave region = rows wv*16 .. wv*16+15 (LDS linear: base + lane*16B).
    const int srow = lane >> 2;                               // 0..15
    const int schunk = (lane & 3) ^ (srow & 3);               // pre-swizzled src chunk
    const size_t aoff = (size_t)(m0 + wv * 16 + srow) * lda + kz + schunk * 8;
    const size_t boff = (size_t)(n0 + wv * 16 + srow) * ldb + kz + schunk * 8;

    // frag read: row R, k-chunk q -> LDS chunk q ^ (R&3)
    const int frow = lane & 15;
    const int q    = lane >> 4;                                // 0..3
    const int rcol = ((q ^ (frow & 3)) << 3);                  // swizzled chunk*8

    #define STAGE(buf, k0)                                             \
        do {                                                           \
            gload_lds16(A + aoff + (k0), &As[buf][wv * 16 * BK]);      \
            gload_lds16(B + boff + (k0), &Bs[buf][wv * 16 * BK]);      \
        } while (0)

    #define COMPUTE(buf)                                                            \
        do {                                                                        \
            short8 af[4], bf[2];                                                    \
            _Pragma("unroll")                                                       \
            for (int i = 0; i < 4; ++i)                                             \
                af[i] = *(const short8*)&As[buf][(wr * 64 + i * 16 + frow) * BK + rcol]; \
            _Pragma("unroll")                                                       \
            for (int j = 0; j < 2; ++j)                                             \
                bf[j] = *(const short8*)&Bs[buf][(wc * 32 + j * 16 + frow) * BK + rcol]; \
            _Pragma("unroll")                                                       \
            for (int i = 0; i < 4; ++i)                                             \
                _Pragma("unroll")                                                   \
                for (int j = 0; j < 2; ++j)                                         \
                    acc[i][j] = __builtin_amdgcn_mfma_f32_16x16x32_bf16(            \
                        af[i], bf[j], acc[i][j], 0, 0, 0);                          \
        } while (0)

    const int nt = K >> 5;
    int cur = 0;
    STAGE(0, 0);
    for (int t = 0; t < nt - 1; ++t) {
        STAGE(cur ^ 1, (t + 1) << 5);                  // prefetch next tile
        asm volatile("s_waitcnt vmcnt(2)" ::: "memory"); // wait current, keep prefetch in flight
        __builtin_amdgcn_s_barrier();
        __builtin_amdgcn_sched_barrier(0);
        COMPUTE(cur);
        __builtin_amdgcn_s_barrier();                  // all reads of buf[cur] done
        cur ^= 1;
    }
    asm volatile("s_waitcnt vmcnt(0)" ::: "memory");
    __builtin_amdgcn_s_barrier();
    __builtin_amdgcn_sched_barrier(0);
    COMPUTE(cur);

    #undef STAGE
    #undef COMPUTE

    float* Cf = blockIdx.z ? Cf1 : Cf0;
    const bool addb = (bias != nullptr) && (blockIdx.z == 0);

    // C/D layout: col = lane&15, row = (lane>>4)*4 + reg  [m89/m91]
    const int crow0 = (lane >> 4) * 4;
    const int ccol  = lane & 15;
    #pragma unroll
    for (int j = 0; j < 2; ++j) {
        int gcol = n0 + wc * 32 + j * 16 + ccol;
        if (gcol >= N) continue;
        float bv = addb ? bias[gcol] : 0.f;
        #pragma unroll
        for (int i = 0; i < 4; ++i) {
            #pragma unroll
            for (int r = 0; r < 4; ++r) {
                int grow = m0 + wr * 64 + i * 16 + crow0 + r;
                float v = acc[i][j][r] + bv;
                if (relu) v = fmaxf(v, 0.f);
                if (Cf) Cf[(size_t)grow * ldcf + gcol] = v;
                if (Cb) Cb[(size_t)grow * ldcb + gcol] = f2bf(v);
            }
        }
    }
}

// ---------------------------------------------------------------------------
// MFMA banded attention. Block = (b, h, 128-query chunk), 512 threads, 8 waves.
// ---------------------------------------------------------------------------
#define CHUNK 128
#define KSLOT 144            // CHUNK + 16 key slots
#define VT_LD 152            // Vt row stride in u16 (+8 pad)

__global__ __launch_bounds__(512) void attn_kernel(
    const u16* __restrict__ qkv, const unsigned char* __restrict__ pad,
    u16* __restrict__ o)
{
    __shared__ u16 Vt[64 * VT_LD];        // V^T: [d][key slot]
    __shared__ u16 Pl[8 * 16 * 40];       // per-wave P tiles [16][40]
    __shared__ unsigned char padl[KSLOT];

    const int tid = threadIdx.x, lane = tid & 63, wv = tid >> 6;
    const int b = blockIdx.z, h = blockIdx.y, c0 = blockIdx.x * CHUNK;
    const u16* base = qkv + (size_t)b * SEQ * (3 * D);

    for (int s = tid; s < KSLOT * 4; s += 512) {
        int t = s >> 2, dq = (s & 3) * 16;
        int j = c0 - 16 + t; if (j < 0) j = 0;
        const u16* vrow = base + (size_t)j * (3 * D) + 2 * D + h * 64 + dq;
        u16 tmp[16];
        *(u16x8*)&tmp[0] = *(const u16x8*)&vrow[0];
        *(u16x8*)&tmp[8] = *(const u16x8*)&vrow[8];
        #pragma unroll
        for (int d = 0; d < 16; ++d)
            Vt[(dq + d) * VT_LD + t] = tmp[d];
    }
    if (tid < KSLOT) {
        int j = c0 - 16 + tid;
        padl[tid] = (j >= 0) ? pad[b * SEQ + j] : (unsigned char)1;
    }
    __syncthreads();

    const int qi0 = wv * 16;
    const int i0  = c0 + qi0;
    const int frow = lane & 15;
    const int g    = lane >> 4;
    const int kg8  = g * 8;
    const int g4   = g * 4;

    short8 qf[2];
    #pragma unroll
    for (int kk = 0; kk < 2; ++kk)
        qf[kk] = *(const short8*)&base[(size_t)(i0 + frow) * (3 * D) + h * 64 + kk * 32 + kg8];

    f32x4 sacc[2] = {};
    #pragma unroll
    for (int jb = 0; jb < 2; ++jb) {
        int jrow = i0 - 16 + jb * 16 + frow; if (jrow < 0) jrow = 0;
        const u16* kbase = base + (size_t)jrow * (3 * D) + D + h * 64;
        #pragma unroll
        for (int kk = 0; kk < 2; ++kk) {
            short8 kf = *(const short8*)&kbase[kk * 32 + kg8];
            sacc[jb] = __builtin_amdgcn_mfma_f32_16x16x32_bf16(qf[kk], kf, sacc[jb], 0, 0, 0);
        }
    }

    float sv[2][4];
    #pragma unroll
    for (int jb = 0; jb < 2; ++jb) {
        int s = jb * 16 + frow;
        int jg = i0 - 16 + s;
        bool padk = (jg < 0) || padl[qi0 + s];
        #pragma unroll
        for (int r = 0; r < 4; ++r) {
            int qq = g4 + r;
            bool banned = (s < qq) || (s > qq + 16) || padk;
            sv[jb][r] = sacc[jb][r] * 0.125f + (banned ? -1e9f : 0.f);
        }
    }

    float ex[2][4], rdn[4];
    #pragma unroll
    for (int r = 0; r < 4; ++r) {
        float m = fmaxf(sv[0][r], sv[1][r]);
        #pragma unroll
        for (int off = 1; off < 16; off <<= 1) m = fmaxf(m, __shfl_xor(m, off));
        float e0 = __expf(sv[0][r] - m);
        float e1 = __expf(sv[1][r] - m);
        float dsum = e0 + e1;
        #pragma unroll
        for (int off = 1; off < 16; off <<= 1) dsum += __shfl_xor(dsum, off);
        ex[0][r] = e0; ex[1][r] = e1;
        rdn[r] = 1.f / dsum;
    }

    u16* Pw = &Pl[wv * 640];
    #pragma unroll
    for (int jb = 0; jb < 2; ++jb)
        #pragma unroll
        for (int r = 0; r < 4; ++r)
            Pw[(g4 + r) * 40 + jb * 16 + frow] = f2bf(ex[jb][r]);
    short8 pa = *(const short8*)&Pw[frow * 40 + kg8];

    f32x4 oacc[4] = {};
    #pragma unroll
    for (int nb = 0; nb < 4; ++nb) {
        short8 vf = *(const short8*)&Vt[(nb * 16 + frow) * VT_LD + qi0 + kg8];
        oacc[nb] = __builtin_amdgcn_mfma_f32_16x16x32_bf16(pa, vf, oacc[nb], 0, 0, 0);
    }

    #pragma unroll
    for (int r = 0; r < 4; ++r) {
        size_t row = (size_t)(b * SEQ + i0 + g4 + r);
        #pragma unroll
        for (int nb = 0; nb < 4; ++nb)
            o[row * D + h * 64 + nb * 16 + frow] = f2bf(oacc[nb][r] * rdn[r]);
    }
}

// ---------------------------------------------------------------------------
// Fused residual + LayerNorm: x = LN(xin + d0 [+ d1]) * g + bt; fp32 + bf16 out.
// ---------------------------------------------------------------------------
__global__ __launch_bounds__(256) void resln_kernel(
    const float* __restrict__ xin,
    const float* __restrict__ d0, const float* __restrict__ d1,
    const float* __restrict__ g, const float* __restrict__ bt,
    float* __restrict__ xf, u16* __restrict__ xb)
{
    int row  = blockIdx.x * 4 + (threadIdx.x >> 6);
    int lane = threadIdx.x & 63;
    const float* xr = xin + (size_t)row * D;
    const float* r0 = d0 + (size_t)row * D;
    const float* r1 = d1 ? d1 + (size_t)row * D : nullptr;

    float vals[8];
    float s = 0.f, s2 = 0.f;
    #pragma unroll
    for (int tt = 0; tt < 8; ++tt) {
        int c = lane + tt * 64;
        float y = xr[c] + r0[c];
        if (r1) y += r1[c];
        vals[tt] = y; s += y; s2 += y * y;
    }
    #pragma unroll
    for (int off = 32; off > 0; off >>= 1) {
        s  += __shfl_xor(s, off);
        s2 += __shfl_xor(s2, off);
    }
    float mean = s * (1.f / D);
    float var  = s2 * (1.f / D) - mean * mean;
    float inv  = rsqrtf(fmaxf(var, 0.f) + 1e-5f);
    #pragma unroll
    for (int tt = 0; tt < 8; ++tt) {
        int c = lane + tt * 64;
        float y = (vals[tt] - mean) * inv * g[c] + bt[c];
        xf[(size_t)row * D + c] = y;
        xb[(size_t)row * D + c] = f2bf(y);
    }
}

// ---------------------------------------------------------------------------
__global__ __launch_bounds__(256) void pad_kernel(
    const float* __restrict__ goal, unsigned char* __restrict__ pad)
{
    int row  = blockIdx.x * 4 + (threadIdx.x >> 6);
    int lane = threadIdx.x & 63;
    bool any = false;
    for (int c = lane; c < 300; c += 64)
        any |= (goal[(size_t)row * 300 + c] != -1.0f);
    unsigned long long b = __ballot(any);
    if (lane == 0) pad[row] = (b == 0ull) ? 1 : 0;
}

// ---------------------------------------------------------------------------
// Batched conversions. mode 0: flat f32->bf16; mode 1: flat f32->f32;
// mode 2: f32->bf16 row-padded (srcld->dstld, zero fill); mode 3: bf16 zero.
// ---------------------------------------------------------------------------
struct CvtJob { const float* src; u16* dstb; float* dstf; int n; int mode; int srcld; int dstld; };
struct CvtArgs { CvtJob j[15]; };

__global__ __launch_bounds__(256) void cvt_kernel(CvtArgs a) {
    CvtJob jb = a.j[blockIdx.y];
    int i0 = blockIdx.x * 2048 + threadIdx.x;
    if (jb.mode == 3) {
        #pragma unroll
        for (int t = 0; t < 8; ++t) { int i = i0 + t * 256; if (i < jb.n) jb.dstb[i] = 0; }
    } else if (jb.mode == 2) {
        #pragma unroll
        for (int t = 0; t < 8; ++t) {
            int i = i0 + t * 256;
            if (i < jb.n) {
                int r = i / jb.dstld, c = i - r * jb.dstld;
                jb.dstb[i] = (c < jb.srcld) ? f2bf(jb.src[(size_t)r * jb.srcld + c]) : (u16)0;
            }
        }
    } else if (jb.mode == 1) {
        #pragma unroll
        for (int t = 0; t < 8; ++t) { int i = i0 + t * 256; if (i < jb.n) jb.dstf[i] = jb.src[i]; }
    } else {
        #pragma unroll
        for (int t = 0; t < 8; ++t) { int i = i0 + t * 256; if (i < jb.n) jb.dstb[i] = f2bf(jb.src[i]); }
    }
}

// ---------------------------------------------------------------------------

extern "C" void kernel_launch(void* const* d_in, const int* in_sizes, int n_in,
                              void* d_out, int out_size, void* d_ws, size_t ws_size,
                              hipStream_t stream)
{
    const float* state  = (const float*)d_in[0];
    const float* goal   = (const float*)d_in[1];
    const float* W_obs  = (const float*)d_in[2];
    const float* b_obs  = (const float*)d_in[3];
    const float* W_lang = (const float*)d_in[4];
    const float* b_lang = (const float*)d_in[5];
    const float* W_in   = (const float*)d_in[6];
    const float* b_in   = (const float*)d_in[7];
    const float* Wqkv   = (const float*)d_in[8];
    const float* bqkv   = (const float*)d_in[9];
    const float* Wo     = (const float*)d_in[10];
    const float* bo     = (const float*)d_in[11];
    const float* W1     = (const float*)d_in[12];
    const float* b1     = (const float*)d_in[13];
    const float* W2     = (const float*)d_in[14];
    const float* b2     = (const float*)d_in[15];
    const float* g1     = (const float*)d_in[16];
    const float* bt1    = (const float*)d_in[17];
    const float* g2     = (const float*)d_in[18];
    const float* bt2    = (const float*)d_in[19];
    const float* W_outp = (const float*)d_in[20];
    const float* b_outp = (const float*)d_in[21];
    const float* W_a1   = (const float*)d_in[22];
    const float* b_a1   = (const float*)d_in[23];
    const float* W_a2   = (const float*)d_in[24];
    const float* b_a2   = (const float*)d_in[25];

    char* ws = (char*)d_ws;
    size_t off = 0;
    auto alloc = [&](size_t bytes) -> void* {
        void* p = ws + off;
        off = (off + bytes + 255) & ~(size_t)255;
        return p;
    };

    u16* wqkv_b  = (u16*)alloc((size_t)NL * 1536 * D * 2);
    u16* wo_b    = (u16*)alloc((size_t)NL * D * D * 2);
    u16* w1_b    = (u16*)alloc((size_t)NL * FFD * D * 2);
    u16* w2_b    = (u16*)alloc((size_t)NL * D * FFD * 2);
    u16* wobs_b  = (u16*)alloc((size_t)256 * 768 * 2);
    u16* wlang_b = (u16*)alloc((size_t)256 * 320 * 2);
    u16* win_b   = (u16*)alloc((size_t)D * D * 2);
    u16* woutp_b = (u16*)alloc((size_t)HID * D * 2);
    u16* wa_b    = (u16*)alloc((size_t)NOUTP * HID * 2);   // padded to 128 rows
    float* ba_f  = (float*)alloc((size_t)NOUT * 4);
    u16* state_b = (u16*)alloc((size_t)MTOK * 768 * 2);    // 12.6 MB \ after input
    u16* goal_b  = (u16*)alloc((size_t)MTOK * 320 * 2);    //  5.2 MB / stage: dead
    u16* feat_b  = (u16*)alloc((size_t)MTOK * D * 2);
    float* x_f   = (float*)alloc((size_t)MTOK * D * 4);
    u16* x_b     = (u16*)alloc((size_t)MTOK * D * 2);
    u16* qkv_b   = (u16*)alloc((size_t)MTOK * 3 * D * 2);
    u16* o_b     = (u16*)alloc((size_t)MTOK * D * 2);
    float* delta_f = (float*)alloc((size_t)MTOK * D * 4);
    u16* h1_b    = (u16*)alloc((size_t)MTOK * FFD * 2);
    u16* hout_b  = (u16*)alloc((size_t)MTOK * HID * 2);
    unsigned char* pad_u8 = (unsigned char*)alloc(MTOK);
    // second split-K partial aliases the dead state_b/goal_b region (17.8 MB >= 16.8 MB)
    float* delta2_f = (float*)state_b;
    (void)ws_size; (void)in_sizes; (void)n_in; (void)out_size;

    // ---- conversions (one batched launch) ----
    CvtArgs ca;
    int nj = 0;
    auto addj = [&](const float* s, u16* db, float* df, int n, int mode, int sld, int dld) {
        ca.j[nj].src = s; ca.j[nj].dstb = db; ca.j[nj].dstf = df;
        ca.j[nj].n = n; ca.j[nj].mode = mode; ca.j[nj].srcld = sld; ca.j[nj].dstld = dld;
        ++nj;
    };
    addj(state,  state_b, nullptr, MTOK * 768, 0, 0, 0);
    addj(goal,   goal_b,  nullptr, MTOK * 320, 2, 300, 320);
    addj(Wqkv,   wqkv_b,  nullptr, NL * 1536 * D, 0, 0, 0);
    addj(Wo,     wo_b,    nullptr, NL * D * D, 0, 0, 0);
    addj(W1,     w1_b,    nullptr, NL * FFD * D, 0, 0, 0);
    addj(W2,     w2_b,    nullptr, NL * D * FFD, 0, 0, 0);
    addj(W_obs,  wobs_b,  nullptr, 256 * 768, 0, 0, 0);
    addj(W_lang, wlang_b, nullptr, 256 * 320, 2, 300, 320);
    addj(W_in,   win_b,   nullptr, D * D, 0, 0, 0);
    addj(W_outp, woutp_b, nullptr, HID * D, 0, 0, 0);
    addj(W_a1,   wa_b,            nullptr, 12 * HID, 0, 0, 0);
    addj(W_a2,   wa_b + 12 * HID, nullptr, 89 * HID, 0, 0, 0);
    addj(nullptr, wa_b + NOUT * HID, nullptr, (NOUTP - NOUT) * HID, 3, 0, 0);
    addj(b_a1,   nullptr, ba_f,      12, 1, 0, 0);
    addj(b_a2,   nullptr, ba_f + 12, 89, 1, 0, 0);
    {
        dim3 grid((MTOK * 768 + 2047) / 2048, 15);
        cvt_kernel<<<grid, 256, 0, stream>>>(ca);
    }

    pad_kernel<<<MTOK / 4, 256, 0, stream>>>(goal, pad_u8);

    // ksplit: 1 = normal; 2 = split-K halves into (Cf0, Cf1), bias in chunk 0
    auto gemm = [&](const u16* A, int lda, const u16* B, int ldb, const float* bias,
                    float* Cf0, float* Cf1, int ldcf, u16* Cb, int ldcb,
                    int N, int K, int relu, int ksplit) {
        dim3 grid((N + BN - 1) / BN, MTOK / BM, ksplit);
        gemm_kernel<<<grid, 512, 0, stream>>>(A, lda, B, ldb, bias, Cf0, Cf1, ldcf,
                                              Cb, ldcb, MTOK, N, K / ksplit, relu);
    };

    // input projections -> feat (obs cols 0:256, lang cols 256:512)
    gemm(state_b, 768, wobs_b, 768, b_obs, nullptr, nullptr, 0, feat_b, D, 256, 768, 0, 1);
    gemm(goal_b, 320, wlang_b, 320, b_lang, nullptr, nullptr, 0, feat_b + 256, D, 256, 320, 0, 1);
    gemm(feat_b, D, win_b, D, b_in, x_f, nullptr, D, x_b, D, D, D, 0, 1);

    for (int l = 0; l < NL; ++l) {
        gemm(x_b, D, wqkv_b + (size_t)l * 1536 * D, D, bqkv + l * 1536,
             nullptr, nullptr, 0, qkv_b, 3 * D, 3 * D, D, 0, 1);
        {
            dim3 grid(SEQ / CHUNK, H, BATCH);
            attn_kernel<<<grid, 512, 0, stream>>>(qkv_b, pad_u8, o_b);
        }
        gemm(o_b, D, wo_b + (size_t)l * D * D, D, bo + l * D,
             delta_f, delta2_f, D, nullptr, 0, D, D, 0, 2);
        resln_kernel<<<MTOK / 4, 256, 0, stream>>>(x_f, delta_f, delta2_f,
                                                   g1 + l * D, bt1 + l * D, x_f, x_b);
        gemm(x_b, D, w1_b + (size_t)l * FFD * D, D, b1 + l * FFD,
             nullptr, nullptr, 0, h1_b, FFD, FFD, D, 1, 1);
        gemm(h1_b, FFD, w2_b + (size_t)l * D * FFD, FFD, b2 + l * D,
             delta_f, delta2_f, D, nullptr, 0, D, FFD, 0, 2);
        resln_kernel<<<MTOK / 4, 256, 0, stream>>>(x_f, delta_f, delta2_f,
                                                   g2 + l * D, bt2 + l * D, x_f, x_b);
    }

    // output head
    gemm(x_b, D, woutp_b, D, b_outp, nullptr, nullptr, 0, hout_b, HID, HID, D, 0, 1);
    gemm(hout_b, HID, wa_b, HID, ba_f, (float*)d_out, nullptr, NOUT, nullptr, 0, NOUT, HID, 0, 1);
}

// Round 5
// 458.632 us; speedup vs baseline: 2.0303x; 1.0205x over previous
//
#include <hip/hip_runtime.h>

#define D 512
#define H 8
#define NL 3
#define FFD 2048
#define HID 256
#define BAND 17
#define BATCH 16
#define SEQ 512
#define MTOK (BATCH * SEQ)   // 8192
#define NOUT 101             // 12 + 89
#define NOUTP 128            // NOUT padded to 128 rows

typedef unsigned short u16;
typedef __attribute__((ext_vector_type(8))) short short8;     // bf16x8 MFMA frag
typedef __attribute__((ext_vector_type(4))) float f32x4;
typedef __attribute__((ext_vector_type(8))) unsigned short u16x8;

__device__ inline float bf2f(u16 u) {
    union { unsigned int i; float f; } x; x.i = ((unsigned int)u) << 16; return x.f;
}
__device__ inline u16 f2bf(float f) {
    union { float f; unsigned int i; } x; x.f = f;
    unsigned int r = x.i + 0x7fffu + ((x.i >> 16) & 1u);
    return (u16)(r >> 16);
}

// async global->LDS, 16B per lane; LDS dest = wave-uniform base + lane*16
__device__ __forceinline__ void gload_lds16(const u16* g, u16* l) {
    __builtin_amdgcn_global_load_lds(
        (const __attribute__((address_space(1))) unsigned int*)(g),
        (__attribute__((address_space(3))) unsigned int*)(l),
        16, 0, 0);
}

// ---------------------------------------------------------------------------
// bf16 MFMA GEMM, 512 threads / 8 waves, 128x128 tile, BK=32.
// Double-buffered LDS + counted vmcnt(2) prefetch (never drain to 0 in loop).
// 16B-chunk XOR swizzle applied on BOTH sides (pre-swizzled global source +
// swizzled ds_read). Split-K via blockIdx.z. Bijective XCD swizzle on (x,y).
// ---------------------------------------------------------------------------
#define BM 128
#define BN 128
#define BK 32

__global__ __launch_bounds__(512) void gemm_kernel(
    const u16* __restrict__ A, int lda,
    const u16* __restrict__ B, int ldb,
    const float* __restrict__ bias,
    float* __restrict__ Cf0, float* __restrict__ Cf1, int ldcf,
    u16* __restrict__ Cb, int ldcb,
    int M, int N, int K, int relu)
{
    __shared__ u16 As[2][BM * BK];   // 2 x 8 KB
    __shared__ u16 Bs[2][BN * BK];
    const int tid  = threadIdx.x;
    const int lane = tid & 63;
    const int wv   = tid >> 6;          // 0..7
    const int wr = wv >> 2, wc = wv & 3; // wave tile: 64 rows x 32 cols

    // XCD-aware bijective swizzle (nb % 8 == 0)
    const int nb  = gridDim.x * gridDim.y;
    const int bid = blockIdx.y * gridDim.x + blockIdx.x;
    const int tile = (bid & 7) * (nb >> 3) + (bid >> 3);
    const int m0 = (tile / gridDim.x) * BM;
    const int n0 = (tile % gridDim.x) * BN;
    const int kz = blockIdx.z * K;

    f32x4 acc[4][2] = {};

    const int srow = lane >> 2;                               // 0..15
    const int schunk = (lane & 3) ^ (srow & 3);               // pre-swizzled src chunk
    const size_t aoff = (size_t)(m0 + wv * 16 + srow) * lda + kz + schunk * 8;
    const size_t boff = (size_t)(n0 + wv * 16 + srow) * ldb + kz + schunk * 8;

    const int frow = lane & 15;
    const int q    = lane >> 4;                                // 0..3
    const int rcol = ((q ^ (frow & 3)) << 3);                  // swizzled chunk*8

    #define STAGE(buf, k0)                                             \
        do {                                                           \
            gload_lds16(A + aoff + (k0), &As[buf][wv * 16 * BK]);      \
            gload_lds16(B + boff + (k0), &Bs[buf][wv * 16 * BK]);      \
        } while (0)

    #define COMPUTE(buf)                                                            \
        do {                                                                        \
            short8 af[4], bf[2];                                                    \
            _Pragma("unroll")                                                       \
            for (int i = 0; i < 4; ++i)                                             \
                af[i] = *(const short8*)&As[buf][(wr * 64 + i * 16 + frow) * BK + rcol]; \
            _Pragma("unroll")                                                       \
            for (int j = 0; j < 2; ++j)                                             \
                bf[j] = *(const short8*)&Bs[buf][(wc * 32 + j * 16 + frow) * BK + rcol]; \
            _Pragma("unroll")                                                       \
            for (int i = 0; i < 4; ++i)                                             \
                _Pragma("unroll")                                                   \
                for (int j = 0; j < 2; ++j)                                         \
                    acc[i][j] = __builtin_amdgcn_mfma_f32_16x16x32_bf16(            \
                        af[i], bf[j], acc[i][j], 0, 0, 0);                          \
        } while (0)

    const int nt = K >> 5;
    int cur = 0;
    STAGE(0, 0);
    for (int t = 0; t < nt - 1; ++t) {
        STAGE(cur ^ 1, (t + 1) << 5);                  // prefetch next tile
        asm volatile("s_waitcnt vmcnt(2)" ::: "memory"); // wait current, keep prefetch in flight
        __builtin_amdgcn_s_barrier();
        __builtin_amdgcn_sched_barrier(0);
        COMPUTE(cur);
        __builtin_amdgcn_s_barrier();                  // all reads of buf[cur] done
        cur ^= 1;
    }
    asm volatile("s_waitcnt vmcnt(0)" ::: "memory");
    __builtin_amdgcn_s_barrier();
    __builtin_amdgcn_sched_barrier(0);
    COMPUTE(cur);

    #undef STAGE
    #undef COMPUTE

    float* Cf = blockIdx.z ? Cf1 : Cf0;
    const bool addb = (bias != nullptr) && (blockIdx.z == 0);

    // C/D layout: col = lane&15, row = (lane>>4)*4 + reg  [m89/m91]
    const int crow0 = (lane >> 4) * 4;
    const int ccol  = lane & 15;
    #pragma unroll
    for (int j = 0; j < 2; ++j) {
        int gcol = n0 + wc * 32 + j * 16 + ccol;
        if (gcol >= N) continue;
        float bv = addb ? bias[gcol] : 0.f;
        #pragma unroll
        for (int i = 0; i < 4; ++i) {
            #pragma unroll
            for (int r = 0; r < 4; ++r) {
                int grow = m0 + wr * 64 + i * 16 + crow0 + r;
                float v = acc[i][j][r] + bv;
                if (relu) v = fmaxf(v, 0.f);
                if (Cf) Cf[(size_t)grow * ldcf + gcol] = v;
                if (Cb) Cb[(size_t)grow * ldcb + gcol] = f2bf(v);
            }
        }
    }
}

// ---------------------------------------------------------------------------
// MFMA banded attention. Block = (b, h, 128-query chunk), 512 threads, 8 waves.
// ---------------------------------------------------------------------------
#define CHUNK 128
#define KSLOT 144            // CHUNK + 16 key slots
#define VT_LD 152            // Vt row stride in u16 (+8 pad)

__global__ __launch_bounds__(512) void attn_kernel(
    const u16* __restrict__ qkv, const unsigned char* __restrict__ pad,
    u16* __restrict__ o)
{
    __shared__ u16 Vt[64 * VT_LD];        // V^T: [d][key slot]
    __shared__ u16 Pl[8 * 16 * 40];       // per-wave P tiles [16][40]
    __shared__ unsigned char padl[KSLOT];

    const int tid = threadIdx.x, lane = tid & 63, wv = tid >> 6;
    const int b = blockIdx.z, h = blockIdx.y, c0 = blockIdx.x * CHUNK;
    const u16* base = qkv + (size_t)b * SEQ * (3 * D);

    for (int s = tid; s < KSLOT * 4; s += 512) {
        int t = s >> 2, dq = (s & 3) * 16;
        int j = c0 - 16 + t; if (j < 0) j = 0;
        const u16* vrow = base + (size_t)j * (3 * D) + 2 * D + h * 64 + dq;
        u16 tmp[16];
        *(u16x8*)&tmp[0] = *(const u16x8*)&vrow[0];
        *(u16x8*)&tmp[8] = *(const u16x8*)&vrow[8];
        #pragma unroll
        for (int d = 0; d < 16; ++d)
            Vt[(dq + d) * VT_LD + t] = tmp[d];
    }
    if (tid < KSLOT) {
        int j = c0 - 16 + tid;
        padl[tid] = (j >= 0) ? pad[b * SEQ + j] : (unsigned char)1;
    }
    __syncthreads();

    const int qi0 = wv * 16;
    const int i0  = c0 + qi0;
    const int frow = lane & 15;
    const int g    = lane >> 4;
    const int kg8  = g * 8;
    const int g4   = g * 4;

    short8 qf[2];
    #pragma unroll
    for (int kk = 0; kk < 2; ++kk)
        qf[kk] = *(const short8*)&base[(size_t)(i0 + frow) * (3 * D) + h * 64 + kk * 32 + kg8];

    f32x4 sacc[2] = {};
    #pragma unroll
    for (int jb = 0; jb < 2; ++jb) {
        int jrow = i0 - 16 + jb * 16 + frow; if (jrow < 0) jrow = 0;
        const u16* kbase = base + (size_t)jrow * (3 * D) + D + h * 64;
        #pragma unroll
        for (int kk = 0; kk < 2; ++kk) {
            short8 kf = *(const short8*)&kbase[kk * 32 + kg8];
            sacc[jb] = __builtin_amdgcn_mfma_f32_16x16x32_bf16(qf[kk], kf, sacc[jb], 0, 0, 0);
        }
    }

    float sv[2][4];
    #pragma unroll
    for (int jb = 0; jb < 2; ++jb) {
        int s = jb * 16 + frow;
        int jg = i0 - 16 + s;
        bool padk = (jg < 0) || padl[qi0 + s];
        #pragma unroll
        for (int r = 0; r < 4; ++r) {
            int qq = g4 + r;
            bool banned = (s < qq) || (s > qq + 16) || padk;
            sv[jb][r] = sacc[jb][r] * 0.125f + (banned ? -1e9f : 0.f);
        }
    }

    float ex[2][4], rdn[4];
    #pragma unroll
    for (int r = 0; r < 4; ++r) {
        float m = fmaxf(sv[0][r], sv[1][r]);
        #pragma unroll
        for (int off = 1; off < 16; off <<= 1) m = fmaxf(m, __shfl_xor(m, off));
        float e0 = __expf(sv[0][r] - m);
        float e1 = __expf(sv[1][r] - m);
        float dsum = e0 + e1;
        #pragma unroll
        for (int off = 1; off < 16; off <<= 1) dsum += __shfl_xor(dsum, off);
        ex[0][r] = e0; ex[1][r] = e1;
        rdn[r] = 1.f / dsum;
    }

    u16* Pw = &Pl[wv * 640];
    #pragma unroll
    for (int jb = 0; jb < 2; ++jb)
        #pragma unroll
        for (int r = 0; r < 4; ++r)
            Pw[(g4 + r) * 40 + jb * 16 + frow] = f2bf(ex[jb][r]);
    short8 pa = *(const short8*)&Pw[frow * 40 + kg8];

    f32x4 oacc[4] = {};
    #pragma unroll
    for (int nb = 0; nb < 4; ++nb) {
        short8 vf = *(const short8*)&Vt[(nb * 16 + frow) * VT_LD + qi0 + kg8];
        oacc[nb] = __builtin_amdgcn_mfma_f32_16x16x32_bf16(pa, vf, oacc[nb], 0, 0, 0);
    }

    #pragma unroll
    for (int r = 0; r < 4; ++r) {
        size_t row = (size_t)(b * SEQ + i0 + g4 + r);
        #pragma unroll
        for (int nb = 0; nb < 4; ++nb)
            o[row * D + h * 64 + nb * 16 + frow] = f2bf(oacc[nb][r] * rdn[r]);
    }
}

// ---------------------------------------------------------------------------
// Fused residual + LayerNorm (vectorized): x = LN(xin + d0 + d1) * g + bt.
// One wave per row of 512; lane owns 8 contiguous elements (16B accesses).
// ---------------------------------------------------------------------------
__global__ __launch_bounds__(256) void resln_kernel(
    const float* __restrict__ xin,
    const float* __restrict__ d0, const float* __restrict__ d1,
    const float* __restrict__ g, const float* __restrict__ bt,
    float* __restrict__ xf, u16* __restrict__ xb)
{
    int row  = blockIdx.x * 4 + (threadIdx.x >> 6);
    int lane = threadIdx.x & 63;
    const f32x4* xr = (const f32x4*)(xin + (size_t)row * D);
    const f32x4* r0 = (const f32x4*)(d0 + (size_t)row * D);
    const f32x4* r1 = (const f32x4*)(d1 + (size_t)row * D);

    f32x4 y0 = xr[lane * 2]     + r0[lane * 2]     + r1[lane * 2];
    f32x4 y1 = xr[lane * 2 + 1] + r0[lane * 2 + 1] + r1[lane * 2 + 1];

    float s = 0.f, s2 = 0.f;
    #pragma unroll
    for (int c = 0; c < 4; ++c) {
        s  += y0[c] + y1[c];
        s2 += y0[c] * y0[c] + y1[c] * y1[c];
    }
    #pragma unroll
    for (int off = 32; off > 0; off >>= 1) {
        s  += __shfl_xor(s, off);
        s2 += __shfl_xor(s2, off);
    }
    float mean = s * (1.f / D);
    float var  = s2 * (1.f / D) - mean * mean;
    float inv  = rsqrtf(fmaxf(var, 0.f) + 1e-5f);

    f32x4 gv0 = ((const f32x4*)g)[lane * 2],  gv1 = ((const f32x4*)g)[lane * 2 + 1];
    f32x4 bv0 = ((const f32x4*)bt)[lane * 2], bv1 = ((const f32x4*)bt)[lane * 2 + 1];
    f32x4 z0, z1;
    #pragma unroll
    for (int c = 0; c < 4; ++c) {
        z0[c] = (y0[c] - mean) * inv * gv0[c] + bv0[c];
        z1[c] = (y1[c] - mean) * inv * gv1[c] + bv1[c];
    }
    ((f32x4*)(xf + (size_t)row * D))[lane * 2]     = z0;
    ((f32x4*)(xf + (size_t)row * D))[lane * 2 + 1] = z1;
    u16x8 ob;
    #pragma unroll
    for (int c = 0; c < 4; ++c) { ob[c] = f2bf(z0[c]); ob[c + 4] = f2bf(z1[c]); }
    *(u16x8*)(xb + (size_t)row * D + lane * 8) = ob;
}

// ---------------------------------------------------------------------------
// pad[b*512+i] = 1 iff all 300 goal entries == -1. Vectorized float4 reads.
// Row stride 1200B (16B aligned).
// ---------------------------------------------------------------------------
__global__ __launch_bounds__(256) void pad_kernel(
    const float* __restrict__ goal, unsigned char* __restrict__ pad)
{
    int row  = blockIdx.x * 4 + (threadIdx.x >> 6);
    int lane = threadIdx.x & 63;
    const f32x4* gr = (const f32x4*)(goal + (size_t)row * 300);
    bool any = false;
    for (int c4 = lane; c4 < 75; c4 += 64) {
        f32x4 v = gr[c4];
        any |= (v[0] != -1.f) | (v[1] != -1.f) | (v[2] != -1.f) | (v[3] != -1.f);
    }
    unsigned long long b = __ballot(any);
    if (lane == 0) pad[row] = (b == 0ull) ? 1 : 0;
}

// ---------------------------------------------------------------------------
// Batched conversions, flat grid with per-job block prefix. 8 elems/thread.
// mode 0: f32->bf16; mode 1: f32->f32 (tiny); mode 2: f32->bf16 row-padded
// 300->320 (constants hardcoded -> magic-mul div); mode 3: bf16 zero-fill.
// ---------------------------------------------------------------------------
struct CvtJob { const float* src; u16* dstb; float* dstf; int n; int mode; };
struct CvtArgs { CvtJob j[15]; int blk0[16]; };

__global__ __launch_bounds__(256) void cvt_kernel(CvtArgs a) {
    const int bx = blockIdx.x;
    int jid = 0;
    #pragma unroll 1
    while (jid < 14 && bx >= a.blk0[jid + 1]) ++jid;
    const CvtJob jb = a.j[jid];
    const int i0 = (bx - a.blk0[jid]) * 2048 + threadIdx.x * 8;
    if (i0 >= jb.n) return;

    if (jb.mode == 0) {
        if (i0 + 8 <= jb.n) {
            f32x4 v0 = *(const f32x4*)(jb.src + i0);
            f32x4 v1 = *(const f32x4*)(jb.src + i0 + 4);
            u16x8 o;
            #pragma unroll
            for (int c = 0; c < 4; ++c) { o[c] = f2bf(v0[c]); o[c + 4] = f2bf(v1[c]); }
            *(u16x8*)(jb.dstb + i0) = o;
        } else {
            for (int e = 0; e < 8 && i0 + e < jb.n; ++e) jb.dstb[i0 + e] = f2bf(jb.src[i0 + e]);
        }
    } else if (jb.mode == 2) {
        // dst rows of 320, src rows of 300; chunk of 8 never crosses a dst row
        int r = (int)((unsigned)i0 / 320u);      // compile-time magic-mul
        int c = i0 - r * 320;
        const float* s = jb.src + (size_t)r * 300 + c;
        u16x8 o;
        if (c + 8 <= 300) {
            f32x4 v0 = *(const f32x4*)s;         // (r*300+c)*4 % 16 == 0
            f32x4 v1 = *(const f32x4*)(s + 4);
            #pragma unroll
            for (int cc = 0; cc < 4; ++cc) { o[cc] = f2bf(v0[cc]); o[cc + 4] = f2bf(v1[cc]); }
        } else {
            #pragma unroll
            for (int e = 0; e < 8; ++e) o[e] = (c + e < 300) ? f2bf(s[e]) : (u16)0;
        }
        *(u16x8*)(jb.dstb + i0) = o;
    } else if (jb.mode == 1) {
        for (int e = 0; e < 8 && i0 + e < jb.n; ++e) jb.dstf[i0 + e] = jb.src[i0 + e];
    } else { // mode 3: zero fill (n multiple of 8)
        u16x8 z = {0, 0, 0, 0, 0, 0, 0, 0};
        *(u16x8*)(jb.dstb + i0) = z;
    }
}

// ---------------------------------------------------------------------------

extern "C" void kernel_launch(void* const* d_in, const int* in_sizes, int n_in,
                              void* d_out, int out_size, void* d_ws, size_t ws_size,
                              hipStream_t stream)
{
    const float* state  = (const float*)d_in[0];
    const float* goal   = (const float*)d_in[1];
    const float* W_obs  = (const float*)d_in[2];
    const float* b_obs  = (const float*)d_in[3];
    const float* W_lang = (const float*)d_in[4];
    const float* b_lang = (const float*)d_in[5];
    const float* W_in   = (const float*)d_in[6];
    const float* b_in   = (const float*)d_in[7];
    const float* Wqkv   = (const float*)d_in[8];
    const float* bqkv   = (const float*)d_in[9];
    const float* Wo     = (const float*)d_in[10];
    const float* bo     = (const float*)d_in[11];
    const float* W1     = (const float*)d_in[12];
    const float* b1     = (const float*)d_in[13];
    const float* W2     = (const float*)d_in[14];
    const float* b2     = (const float*)d_in[15];
    const float* g1     = (const float*)d_in[16];
    const float* bt1    = (const float*)d_in[17];
    const float* g2     = (const float*)d_in[18];
    const float* bt2    = (const float*)d_in[19];
    const float* W_outp = (const float*)d_in[20];
    const float* b_outp = (const float*)d_in[21];
    const float* W_a1   = (const float*)d_in[22];
    const float* b_a1   = (const float*)d_in[23];
    const float* W_a2   = (const float*)d_in[24];
    const float* b_a2   = (const float*)d_in[25];

    char* ws = (char*)d_ws;
    size_t off = 0;
    auto alloc = [&](size_t bytes) -> void* {
        void* p = ws + off;
        off = (off + bytes + 255) & ~(size_t)255;
        return p;
    };

    u16* wqkv_b  = (u16*)alloc((size_t)NL * 1536 * D * 2);
    u16* wo_b    = (u16*)alloc((size_t)NL * D * D * 2);
    u16* w1_b    = (u16*)alloc((size_t)NL * FFD * D * 2);
    u16* w2_b    = (u16*)alloc((size_t)NL * D * FFD * 2);
    u16* wobs_b  = (u16*)alloc((size_t)256 * 768 * 2);
    u16* wlang_b = (u16*)alloc((size_t)256 * 320 * 2);
    u16* win_b   = (u16*)alloc((size_t)D * D * 2);
    u16* woutp_b = (u16*)alloc((size_t)HID * D * 2);
    u16* wa_b    = (u16*)alloc((size_t)NOUTP * HID * 2);   // padded to 128 rows
    float* ba_f  = (float*)alloc((size_t)NOUT * 4);
    u16* state_b = (u16*)alloc((size_t)MTOK * 768 * 2);    // 12.6 MB \ after input
    u16* goal_b  = (u16*)alloc((size_t)MTOK * 320 * 2);    //  5.2 MB / stage: dead
    u16* feat_b  = (u16*)alloc((size_t)MTOK * D * 2);
    float* x_f   = (float*)alloc((size_t)MTOK * D * 4);
    u16* x_b     = (u16*)alloc((size_t)MTOK * D * 2);
    u16* qkv_b   = (u16*)alloc((size_t)MTOK * 3 * D * 2);
    u16* o_b     = (u16*)alloc((size_t)MTOK * D * 2);
    float* delta_f = (float*)alloc((size_t)MTOK * D * 4);
    u16* h1_b    = (u16*)alloc((size_t)MTOK * FFD * 2);
    u16* hout_b  = (u16*)alloc((size_t)MTOK * HID * 2);
    unsigned char* pad_u8 = (unsigned char*)alloc(MTOK);
    // second split-K partial aliases the dead state_b/goal_b region (17.8 MB >= 16.8 MB)
    float* delta2_f = (float*)state_b;
    (void)ws_size; (void)in_sizes; (void)n_in; (void)out_size;

    // ---- conversions (one batched launch, flat grid) ----
    CvtArgs ca;
    int nj = 0, blks = 0;
    auto addj = [&](const float* s, u16* db, float* df, int n, int mode) {
        ca.j[nj].src = s; ca.j[nj].dstb = db; ca.j[nj].dstf = df;
        ca.j[nj].n = n; ca.j[nj].mode = mode;
        ca.blk0[nj] = blks;
        blks += (n + 2047) / 2048;
        ++nj;
    };
    addj(state,  state_b, nullptr, MTOK * 768, 0);
    addj(goal,   goal_b,  nullptr, MTOK * 320, 2);
    addj(Wqkv,   wqkv_b,  nullptr, NL * 1536 * D, 0);
    addj(Wo,     wo_b,    nullptr, NL * D * D, 0);
    addj(W1,     w1_b,    nullptr, NL * FFD * D, 0);
    addj(W2,     w2_b,    nullptr, NL * D * FFD, 0);
    addj(W_obs,  wobs_b,  nullptr, 256 * 768, 0);
    addj(W_lang, wlang_b, nullptr, 256 * 320, 2);
    addj(W_in,   win_b,   nullptr, D * D, 0);
    addj(W_outp, woutp_b, nullptr, HID * D, 0);
    addj(W_a1,   wa_b,            nullptr, 12 * HID, 0);
    addj(W_a2,   wa_b + 12 * HID, nullptr, 89 * HID, 0);
    addj(nullptr, wa_b + NOUT * HID, nullptr, (NOUTP - NOUT) * HID, 3);
    addj(b_a1,   nullptr, ba_f,      12, 1);
    addj(b_a2,   nullptr, ba_f + 12, 89, 1);
    ca.blk0[nj] = blks;
    cvt_kernel<<<blks, 256, 0, stream>>>(ca);

    pad_kernel<<<MTOK / 4, 256, 0, stream>>>(goal, pad_u8);

    // ksplit: 1 = normal; 2 = split-K halves into (Cf0, Cf1), bias in chunk 0
    auto gemm = [&](const u16* A, int lda, const u16* B, int ldb, const float* bias,
                    float* Cf0, float* Cf1, int ldcf, u16* Cb, int ldcb,
                    int N, int K, int relu, int ksplit) {
        dim3 grid((N + BN - 1) / BN, MTOK / BM, ksplit);
        gemm_kernel<<<grid, 512, 0, stream>>>(A, lda, B, ldb, bias, Cf0, Cf1, ldcf,
                                              Cb, ldcb, MTOK, N, K / ksplit, relu);
    };

    // input projections -> feat (obs cols 0:256, lang cols 256:512)
    gemm(state_b, 768, wobs_b, 768, b_obs, nullptr, nullptr, 0, feat_b, D, 256, 768, 0, 1);
    gemm(goal_b, 320, wlang_b, 320, b_lang, nullptr, nullptr, 0, feat_b + 256, D, 256, 320, 0, 1);
    gemm(feat_b, D, win_b, D, b_in, x_f, nullptr, D, x_b, D, D, D, 0, 1);

    for (int l = 0; l < NL; ++l) {
        gemm(x_b, D, wqkv_b + (size_t)l * 1536 * D, D, bqkv + l * 1536,
             nullptr, nullptr, 0, qkv_b, 3 * D, 3 * D, D, 0, 1);
        {
            dim3 grid(SEQ / CHUNK, H, BATCH);
            attn_kernel<<<grid, 512, 0, stream>>>(qkv_b, pad_u8, o_b);
        }
        gemm(o_b, D, wo_b + (size_t)l * D * D, D, bo + l * D,
             delta_f, delta2_f, D, nullptr, 0, D, D, 0, 2);
        resln_kernel<<<MTOK / 4, 256, 0, stream>>>(x_f, delta_f, delta2_f,
                                                   g1 + l * D, bt1 + l * D, x_f, x_b);
        gemm(x_b, D, w1_b + (size_t)l * FFD * D, D, b1 + l * FFD,
             nullptr, nullptr, 0, h1_b, FFD, FFD, D, 1, 1);
        gemm(h1_b, FFD, w2_b + (size_t)l * D * FFD, FFD, b2 + l * D,
             delta_f, delta2_f, D, nullptr, 0, D, FFD, 0, 2);
        resln_kernel<<<MTOK / 4, 256, 0, stream>>>(x_f, delta_f, delta2_f,
                                                   g2 + l * D, bt2 + l * D, x_f, x_b);
    }

    // output head
    gemm(x_b, D, woutp_b, D, b_outp, nullptr, nullptr, 0, hout_b, HID, HID, D, 0, 1);
    gemm(hout_b, HID, wa_b, HID, ba_f, (float*)d_out, nullptr, NOUT, nullptr, 0, NOUT, HID, 0, 1);
}

// Round 6
// 433.418 us; speedup vs baseline: 2.1484x; 1.0582x over previous
//
#include <hip/hip_runtime.h>

#define D 512
#define H 8
#define NL 3
#define FFD 2048
#define HID 256
#define BAND 17
#define BATCH 16
#define SEQ 512
#define MTOK (BATCH * SEQ)   // 8192
#define NOUT 101             // 12 + 89
#define NOUTP 128            // NOUT padded to 128 rows

typedef unsigned short u16;
typedef __attribute__((ext_vector_type(8))) short short8;     // bf16x8 MFMA frag
typedef __attribute__((ext_vector_type(4))) float f32x4;
typedef __attribute__((ext_vector_type(8))) unsigned short u16x8;

__device__ inline float bf2f(u16 u) {
    union { unsigned int i; float f; } x; x.i = ((unsigned int)u) << 16; return x.f;
}
__device__ inline u16 f2bf(float f) {
    union { float f; unsigned int i; } x; x.f = f;
    unsigned int r = x.i + 0x7fffu + ((x.i >> 16) & 1u);
    return (u16)(r >> 16);
}

// async global->LDS, 16B per lane; LDS dest = wave-uniform base + lane*16
__device__ __forceinline__ void gload_lds16(const u16* g, u16* l) {
    __builtin_amdgcn_global_load_lds(
        (const __attribute__((address_space(1))) unsigned int*)(g),
        (__attribute__((address_space(3))) unsigned int*)(l),
        16, 0, 0);
}

// ---------------------------------------------------------------------------
// bf16 MFMA GEMM, 512 threads / 8 waves, 128x128 tile, BK=32.
// TRIPLE-buffered LDS, counted vmcnt(4): two tiles always in flight, each
// load gets ~2 compute phases of latency slack (T4). 16B-chunk XOR swizzle
// on both sides. Split-K via blockIdx.z. Bijective XCD swizzle on (x,y).
// ---------------------------------------------------------------------------
#define BM 128
#define BN 128
#define BK 32

__global__ __launch_bounds__(512) void gemm_kernel(
    const u16* __restrict__ A, int lda,
    const u16* __restrict__ B, int ldb,
    const float* __restrict__ bias,
    float* __restrict__ Cf0, float* __restrict__ Cf1, int ldcf,
    u16* __restrict__ Cb, int ldcb,
    int M, int N, int K, int relu)
{
    __shared__ u16 As[3][BM * BK];   // 3 x 8 KB
    __shared__ u16 Bs[3][BN * BK];
    const int tid  = threadIdx.x;
    const int lane = tid & 63;
    const int wv   = tid >> 6;          // 0..7
    const int wr = wv >> 2, wc = wv & 3; // wave tile: 64 rows x 32 cols

    // XCD-aware bijective swizzle (nb % 8 == 0)
    const int nb  = gridDim.x * gridDim.y;
    const int bid = blockIdx.y * gridDim.x + blockIdx.x;
    const int tile = (bid & 7) * (nb >> 3) + (bid >> 3);
    const int m0 = (tile / gridDim.x) * BM;
    const int n0 = (tile % gridDim.x) * BN;
    const int kz = blockIdx.z * K;

    f32x4 acc[4][2] = {};

    const int srow = lane >> 2;                               // 0..15
    const int schunk = (lane & 3) ^ (srow & 3);               // pre-swizzled src chunk
    const size_t aoff = (size_t)(m0 + wv * 16 + srow) * lda + kz + schunk * 8;
    const size_t boff = (size_t)(n0 + wv * 16 + srow) * ldb + kz + schunk * 8;

    const int frow = lane & 15;
    const int q    = lane >> 4;                                // 0..3
    const int rcol = ((q ^ (frow & 3)) << 3);                  // swizzled chunk*8

    #define STAGE(buf, k0)                                             \
        do {                                                           \
            gload_lds16(A + aoff + (k0), &As[buf][wv * 16 * BK]);      \
            gload_lds16(B + boff + (k0), &Bs[buf][wv * 16 * BK]);      \
        } while (0)

    #define COMPUTE(buf)                                                            \
        do {                                                                        \
            short8 af[4], bf[2];                                                    \
            _Pragma("unroll")                                                       \
            for (int i = 0; i < 4; ++i)                                             \
                af[i] = *(const short8*)&As[buf][(wr * 64 + i * 16 + frow) * BK + rcol]; \
            _Pragma("unroll")                                                       \
            for (int j = 0; j < 2; ++j)                                             \
                bf[j] = *(const short8*)&Bs[buf][(wc * 32 + j * 16 + frow) * BK + rcol]; \
            _Pragma("unroll")                                                       \
            for (int i = 0; i < 4; ++i)                                             \
                _Pragma("unroll")                                                   \
                for (int j = 0; j < 2; ++j)                                         \
                    acc[i][j] = __builtin_amdgcn_mfma_f32_16x16x32_bf16(            \
                        af[i], bf[j], acc[i][j], 0, 0, 0);                          \
        } while (0)

    const int nt = K >> 5;            // >= 8 for all call sites
    STAGE(0, 0);
    STAGE(1, 32);
    int cur = 0;
    for (int t = 0; t < nt - 2; ++t) {
        int s = cur + 2; if (s >= 3) s -= 3;
        STAGE(s, (t + 2) << 5);                          // keep 2 tiles in flight
        asm volatile("s_waitcnt vmcnt(4)" ::: "memory"); // tile t landed; t+1,t+2 in flight
        __builtin_amdgcn_s_barrier();
        __builtin_amdgcn_sched_barrier(0);
        COMPUTE(cur);
        __builtin_amdgcn_s_barrier();                    // all reads of buf done
        ++cur; if (cur >= 3) cur = 0;
    }
    asm volatile("s_waitcnt vmcnt(2)" ::: "memory");
    __builtin_amdgcn_s_barrier();
    __builtin_amdgcn_sched_barrier(0);
    COMPUTE(cur);
    __builtin_amdgcn_s_barrier();
    ++cur; if (cur >= 3) cur = 0;
    asm volatile("s_waitcnt vmcnt(0)" ::: "memory");
    __builtin_amdgcn_s_barrier();
    __builtin_amdgcn_sched_barrier(0);
    COMPUTE(cur);

    #undef STAGE
    #undef COMPUTE

    float* Cf = blockIdx.z ? Cf1 : Cf0;
    const bool addb = (bias != nullptr) && (blockIdx.z == 0);

    // C/D layout: col = lane&15, row = (lane>>4)*4 + reg  [m89/m91]
    const int crow0 = (lane >> 4) * 4;
    const int ccol  = lane & 15;
    #pragma unroll
    for (int j = 0; j < 2; ++j) {
        int gcol = n0 + wc * 32 + j * 16 + ccol;
        if (gcol >= N) continue;
        float bv = addb ? bias[gcol] : 0.f;
        #pragma unroll
        for (int i = 0; i < 4; ++i) {
            #pragma unroll
            for (int r = 0; r < 4; ++r) {
                int grow = m0 + wr * 64 + i * 16 + crow0 + r;
                float v = acc[i][j][r] + bv;
                if (relu) v = fmaxf(v, 0.f);
                if (Cf) Cf[(size_t)grow * ldcf + gcol] = v;
                if (Cb) Cb[(size_t)grow * ldcb + gcol] = f2bf(v);
            }
        }
    }
}

// ---------------------------------------------------------------------------
// MFMA banded attention. Block = (b, h, 128-query chunk), 512 threads, 8 waves.
// ---------------------------------------------------------------------------
#define CHUNK 128
#define KSLOT 144            // CHUNK + 16 key slots
#define VT_LD 152            // Vt row stride in u16 (+8 pad)

__global__ __launch_bounds__(512) void attn_kernel(
    const u16* __restrict__ qkv, const unsigned char* __restrict__ pad,
    u16* __restrict__ o)
{
    __shared__ u16 Vt[64 * VT_LD];        // V^T: [d][key slot]
    __shared__ u16 Pl[8 * 16 * 40];       // per-wave P tiles [16][40]
    __shared__ unsigned char padl[KSLOT];

    const int tid = threadIdx.x, lane = tid & 63, wv = tid >> 6;
    const int b = blockIdx.z, h = blockIdx.y, c0 = blockIdx.x * CHUNK;
    const u16* base = qkv + (size_t)b * SEQ * (3 * D);

    for (int s = tid; s < KSLOT * 4; s += 512) {
        int t = s >> 2, dq = (s & 3) * 16;
        int j = c0 - 16 + t; if (j < 0) j = 0;
        const u16* vrow = base + (size_t)j * (3 * D) + 2 * D + h * 64 + dq;
        u16 tmp[16];
        *(u16x8*)&tmp[0] = *(const u16x8*)&vrow[0];
        *(u16x8*)&tmp[8] = *(const u16x8*)&vrow[8];
        #pragma unroll
        for (int d = 0; d < 16; ++d)
            Vt[(dq + d) * VT_LD + t] = tmp[d];
    }
    if (tid < KSLOT) {
        int j = c0 - 16 + tid;
        padl[tid] = (j >= 0) ? pad[b * SEQ + j] : (unsigned char)1;
    }
    __syncthreads();

    const int qi0 = wv * 16;
    const int i0  = c0 + qi0;
    const int frow = lane & 15;
    const int g    = lane >> 4;
    const int kg8  = g * 8;
    const int g4   = g * 4;

    short8 qf[2];
    #pragma unroll
    for (int kk = 0; kk < 2; ++kk)
        qf[kk] = *(const short8*)&base[(size_t)(i0 + frow) * (3 * D) + h * 64 + kk * 32 + kg8];

    f32x4 sacc[2] = {};
    #pragma unroll
    for (int jb = 0; jb < 2; ++jb) {
        int jrow = i0 - 16 + jb * 16 + frow; if (jrow < 0) jrow = 0;
        const u16* kbase = base + (size_t)jrow * (3 * D) + D + h * 64;
        #pragma unroll
        for (int kk = 0; kk < 2; ++kk) {
            short8 kf = *(const short8*)&kbase[kk * 32 + kg8];
            sacc[jb] = __builtin_amdgcn_mfma_f32_16x16x32_bf16(qf[kk], kf, sacc[jb], 0, 0, 0);
        }
    }

    float sv[2][4];
    #pragma unroll
    for (int jb = 0; jb < 2; ++jb) {
        int s = jb * 16 + frow;
        int jg = i0 - 16 + s;
        bool padk = (jg < 0) || padl[qi0 + s];
        #pragma unroll
        for (int r = 0; r < 4; ++r) {
            int qq = g4 + r;
            bool banned = (s < qq) || (s > qq + 16) || padk;
            sv[jb][r] = sacc[jb][r] * 0.125f + (banned ? -1e9f : 0.f);
        }
    }

    float ex[2][4], rdn[4];
    #pragma unroll
    for (int r = 0; r < 4; ++r) {
        float m = fmaxf(sv[0][r], sv[1][r]);
        #pragma unroll
        for (int off = 1; off < 16; off <<= 1) m = fmaxf(m, __shfl_xor(m, off));
        float e0 = __expf(sv[0][r] - m);
        float e1 = __expf(sv[1][r] - m);
        float dsum = e0 + e1;
        #pragma unroll
        for (int off = 1; off < 16; off <<= 1) dsum += __shfl_xor(dsum, off);
        ex[0][r] = e0; ex[1][r] = e1;
        rdn[r] = 1.f / dsum;
    }

    u16* Pw = &Pl[wv * 640];
    #pragma unroll
    for (int jb = 0; jb < 2; ++jb)
        #pragma unroll
        for (int r = 0; r < 4; ++r)
            Pw[(g4 + r) * 40 + jb * 16 + frow] = f2bf(ex[jb][r]);
    short8 pa = *(const short8*)&Pw[frow * 40 + kg8];

    f32x4 oacc[4] = {};
    #pragma unroll
    for (int nb = 0; nb < 4; ++nb) {
        short8 vf = *(const short8*)&Vt[(nb * 16 + frow) * VT_LD + qi0 + kg8];
        oacc[nb] = __builtin_amdgcn_mfma_f32_16x16x32_bf16(pa, vf, oacc[nb], 0, 0, 0);
    }

    #pragma unroll
    for (int r = 0; r < 4; ++r) {
        size_t row = (size_t)(b * SEQ + i0 + g4 + r);
        #pragma unroll
        for (int nb = 0; nb < 4; ++nb)
            o[row * D + h * 64 + nb * 16 + frow] = f2bf(oacc[nb][r] * rdn[r]);
    }
}

// ---------------------------------------------------------------------------
// Fused residual + LayerNorm, bf16 residual stream:
// x = LN(bf2f(xin_b) + d0 + d1) * g + bt; writes bf16 only.
// ---------------------------------------------------------------------------
__global__ __launch_bounds__(256) void resln_kernel(
    const u16* __restrict__ xin,
    const float* __restrict__ d0, const float* __restrict__ d1,
    const float* __restrict__ g, const float* __restrict__ bt,
    u16* __restrict__ xb)
{
    int row  = blockIdx.x * 4 + (threadIdx.x >> 6);
    int lane = threadIdx.x & 63;
    const f32x4* r0 = (const f32x4*)(d0 + (size_t)row * D);
    const f32x4* r1 = (const f32x4*)(d1 + (size_t)row * D);
    u16x8 xv = *(const u16x8*)(xin + (size_t)row * D + lane * 8);

    f32x4 y0 = r0[lane * 2]     + r1[lane * 2];
    f32x4 y1 = r0[lane * 2 + 1] + r1[lane * 2 + 1];
    #pragma unroll
    for (int c = 0; c < 4; ++c) { y0[c] += bf2f(xv[c]); y1[c] += bf2f(xv[c + 4]); }

    float s = 0.f, s2 = 0.f;
    #pragma unroll
    for (int c = 0; c < 4; ++c) {
        s  += y0[c] + y1[c];
        s2 += y0[c] * y0[c] + y1[c] * y1[c];
    }
    #pragma unroll
    for (int off = 32; off > 0; off >>= 1) {
        s  += __shfl_xor(s, off);
        s2 += __shfl_xor(s2, off);
    }
    float mean = s * (1.f / D);
    float var  = s2 * (1.f / D) - mean * mean;
    float inv  = rsqrtf(fmaxf(var, 0.f) + 1e-5f);

    f32x4 gv0 = ((const f32x4*)g)[lane * 2],  gv1 = ((const f32x4*)g)[lane * 2 + 1];
    f32x4 bv0 = ((const f32x4*)bt)[lane * 2], bv1 = ((const f32x4*)bt)[lane * 2 + 1];
    u16x8 ob;
    #pragma unroll
    for (int c = 0; c < 4; ++c) {
        ob[c]     = f2bf((y0[c] - mean) * inv * gv0[c] + bv0[c]);
        ob[c + 4] = f2bf((y1[c] - mean) * inv * gv1[c] + bv1[c]);
    }
    *(u16x8*)(xb + (size_t)row * D + lane * 8) = ob;
}

// ---------------------------------------------------------------------------
// pad[b*512+i] = 1 iff all 300 goal entries == -1. Vectorized float4 reads.
// ---------------------------------------------------------------------------
__global__ __launch_bounds__(256) void pad_kernel(
    const float* __restrict__ goal, unsigned char* __restrict__ pad)
{
    int row  = blockIdx.x * 4 + (threadIdx.x >> 6);
    int lane = threadIdx.x & 63;
    const f32x4* gr = (const f32x4*)(goal + (size_t)row * 300);
    bool any = false;
    for (int c4 = lane; c4 < 75; c4 += 64) {
        f32x4 v = gr[c4];
        any |= (v[0] != -1.f) | (v[1] != -1.f) | (v[2] != -1.f) | (v[3] != -1.f);
    }
    unsigned long long b = __ballot(any);
    if (lane == 0) pad[row] = (b == 0ull) ? 1 : 0;
}

// ---------------------------------------------------------------------------
// Batched conversions, flat grid with per-job block prefix. 8 elems/thread.
// ---------------------------------------------------------------------------
struct CvtJob { const float* src; u16* dstb; float* dstf; int n; int mode; };
struct CvtArgs { CvtJob j[15]; int blk0[16]; };

__global__ __launch_bounds__(256) void cvt_kernel(CvtArgs a) {
    const int bx = blockIdx.x;
    int jid = 0;
    #pragma unroll 1
    while (jid < 14 && bx >= a.blk0[jid + 1]) ++jid;
    const CvtJob jb = a.j[jid];
    const int i0 = (bx - a.blk0[jid]) * 2048 + threadIdx.x * 8;
    if (i0 >= jb.n) return;

    if (jb.mode == 0) {
        if (i0 + 8 <= jb.n) {
            f32x4 v0 = *(const f32x4*)(jb.src + i0);
            f32x4 v1 = *(const f32x4*)(jb.src + i0 + 4);
            u16x8 o;
            #pragma unroll
            for (int c = 0; c < 4; ++c) { o[c] = f2bf(v0[c]); o[c + 4] = f2bf(v1[c]); }
            *(u16x8*)(jb.dstb + i0) = o;
        } else {
            for (int e = 0; e < 8 && i0 + e < jb.n; ++e) jb.dstb[i0 + e] = f2bf(jb.src[i0 + e]);
        }
    } else if (jb.mode == 2) {
        int r = (int)((unsigned)i0 / 320u);
        int c = i0 - r * 320;
        const float* s = jb.src + (size_t)r * 300 + c;
        u16x8 o;
        if (c + 8 <= 300) {
            f32x4 v0 = *(const f32x4*)s;
            f32x4 v1 = *(const f32x4*)(s + 4);
            #pragma unroll
            for (int cc = 0; cc < 4; ++cc) { o[cc] = f2bf(v0[cc]); o[cc + 4] = f2bf(v1[cc]); }
        } else {
            #pragma unroll
            for (int e = 0; e < 8; ++e) o[e] = (c + e < 300) ? f2bf(s[e]) : (u16)0;
        }
        *(u16x8*)(jb.dstb + i0) = o;
    } else if (jb.mode == 1) {
        for (int e = 0; e < 8 && i0 + e < jb.n; ++e) jb.dstf[i0 + e] = jb.src[i0 + e];
    } else { // mode 3: zero fill (n multiple of 8)
        u16x8 z = {0, 0, 0, 0, 0, 0, 0, 0};
        *(u16x8*)(jb.dstb + i0) = z;
    }
}

// ---------------------------------------------------------------------------

extern "C" void kernel_launch(void* const* d_in, const int* in_sizes, int n_in,
                              void* d_out, int out_size, void* d_ws, size_t ws_size,
                              hipStream_t stream)
{
    const float* state  = (const float*)d_in[0];
    const float* goal   = (const float*)d_in[1];
    const float* W_obs  = (const float*)d_in[2];
    const float* b_obs  = (const float*)d_in[3];
    const float* W_lang = (const float*)d_in[4];
    const float* b_lang = (const float*)d_in[5];
    const float* W_in   = (const float*)d_in[6];
    const float* b_in   = (const float*)d_in[7];
    const float* Wqkv   = (const float*)d_in[8];
    const float* bqkv   = (const float*)d_in[9];
    const float* Wo     = (const float*)d_in[10];
    const float* bo     = (const float*)d_in[11];
    const float* W1     = (const float*)d_in[12];
    const float* b1     = (const float*)d_in[13];
    const float* W2     = (const float*)d_in[14];
    const float* b2     = (const float*)d_in[15];
    const float* g1     = (const float*)d_in[16];
    const float* bt1    = (const float*)d_in[17];
    const float* g2     = (const float*)d_in[18];
    const float* bt2    = (const float*)d_in[19];
    const float* W_outp = (const float*)d_in[20];
    const float* b_outp = (const float*)d_in[21];
    const float* W_a1   = (const float*)d_in[22];
    const float* b_a1   = (const float*)d_in[23];
    const float* W_a2   = (const float*)d_in[24];
    const float* b_a2   = (const float*)d_in[25];

    char* ws = (char*)d_ws;
    size_t off = 0;
    auto alloc = [&](size_t bytes) -> void* {
        void* p = ws + off;
        off = (off + bytes + 255) & ~(size_t)255;
        return p;
    };

    u16* wqkv_b  = (u16*)alloc((size_t)NL * 1536 * D * 2);
    u16* wo_b    = (u16*)alloc((size_t)NL * D * D * 2);
    u16* w1_b    = (u16*)alloc((size_t)NL * FFD * D * 2);
    u16* w2_b    = (u16*)alloc((size_t)NL * D * FFD * 2);
    u16* wobs_b  = (u16*)alloc((size_t)256 * 768 * 2);
    u16* wlang_b = (u16*)alloc((size_t)256 * 320 * 2);
    u16* win_b   = (u16*)alloc((size_t)D * D * 2);
    u16* woutp_b = (u16*)alloc((size_t)HID * D * 2);
    u16* wa_b    = (u16*)alloc((size_t)NOUTP * HID * 2);   // padded to 128 rows
    float* ba_f  = (float*)alloc((size_t)NOUT * 4);
    u16* state_b = (u16*)alloc((size_t)MTOK * 768 * 2);    // 12.6 MB \ after input
    u16* goal_b  = (u16*)alloc((size_t)MTOK * 320 * 2);    //  5.2 MB / stage: dead
    u16* feat_b  = (u16*)alloc((size_t)MTOK * D * 2);
    u16* x_b     = (u16*)alloc((size_t)MTOK * D * 2);
    u16* qkv_b   = (u16*)alloc((size_t)MTOK * 3 * D * 2);
    u16* o_b     = (u16*)alloc((size_t)MTOK * D * 2);
    float* delta_f = (float*)alloc((size_t)MTOK * D * 4);
    u16* h1_b    = (u16*)alloc((size_t)MTOK * FFD * 2);
    u16* hout_b  = (u16*)alloc((size_t)MTOK * HID * 2);
    unsigned char* pad_u8 = (unsigned char*)alloc(MTOK);
    // second split-K partial aliases the dead state_b/goal_b region (17.8 MB >= 16.8 MB)
    float* delta2_f = (float*)state_b;
    (void)ws_size; (void)in_sizes; (void)n_in; (void)out_size;

    // ---- conversions (one batched launch, flat grid) ----
    CvtArgs ca;
    int nj = 0, blks = 0;
    auto addj = [&](const float* s, u16* db, float* df, int n, int mode) {
        ca.j[nj].src = s; ca.j[nj].dstb = db; ca.j[nj].dstf = df;
        ca.j[nj].n = n; ca.j[nj].mode = mode;
        ca.blk0[nj] = blks;
        blks += (n + 2047) / 2048;
        ++nj;
    };
    addj(state,  state_b, nullptr, MTOK * 768, 0);
    addj(goal,   goal_b,  nullptr, MTOK * 320, 2);
    addj(Wqkv,   wqkv_b,  nullptr, NL * 1536 * D, 0);
    addj(Wo,     wo_b,    nullptr, NL * D * D, 0);
    addj(W1,     w1_b,    nullptr, NL * FFD * D, 0);
    addj(W2,     w2_b,    nullptr, NL * D * FFD, 0);
    addj(W_obs,  wobs_b,  nullptr, 256 * 768, 0);
    addj(W_lang, wlang_b, nullptr, 256 * 320, 2);
    addj(W_in,   win_b,   nullptr, D * D, 0);
    addj(W_outp, woutp_b, nullptr, HID * D, 0);
    addj(W_a1,   wa_b,            nullptr, 12 * HID, 0);
    addj(W_a2,   wa_b + 12 * HID, nullptr, 89 * HID, 0);
    addj(nullptr, wa_b + NOUT * HID, nullptr, (NOUTP - NOUT) * HID, 3);
    addj(b_a1,   nullptr, ba_f,      12, 1);
    addj(b_a2,   nullptr, ba_f + 12, 89, 1);
    ca.blk0[nj] = blks;
    cvt_kernel<<<blks, 256, 0, stream>>>(ca);

    pad_kernel<<<MTOK / 4, 256, 0, stream>>>(goal, pad_u8);

    // ksplit: 1 = normal; 2 = split-K halves into (Cf0, Cf1), bias in chunk 0
    auto gemm = [&](const u16* A, int lda, const u16* B, int ldb, const float* bias,
                    float* Cf0, float* Cf1, int ldcf, u16* Cb, int ldcb,
                    int N, int K, int relu, int ksplit) {
        dim3 grid((N + BN - 1) / BN, MTOK / BM, ksplit);
        gemm_kernel<<<grid, 512, 0, stream>>>(A, lda, B, ldb, bias, Cf0, Cf1, ldcf,
                                              Cb, ldcb, MTOK, N, K / ksplit, relu);
    };

    // input projections -> feat (obs cols 0:256, lang cols 256:512)
    gemm(state_b, 768, wobs_b, 768, b_obs, nullptr, nullptr, 0, feat_b, D, 256, 768, 0, 1);
    gemm(goal_b, 320, wlang_b, 320, b_lang, nullptr, nullptr, 0, feat_b + 256, D, 256, 320, 0, 1);
    gemm(feat_b, D, win_b, D, b_in, nullptr, nullptr, 0, x_b, D, D, D, 0, 1);

    for (int l = 0; l < NL; ++l) {
        gemm(x_b, D, wqkv_b + (size_t)l * 1536 * D, D, bqkv + l * 1536,
             nullptr, nullptr, 0, qkv_b, 3 * D, 3 * D, D, 0, 1);
        {
            dim3 grid(SEQ / CHUNK, H, BATCH);
            attn_kernel<<<grid, 512, 0, stream>>>(qkv_b, pad_u8, o_b);
        }
        gemm(o_b, D, wo_b + (size_t)l * D * D, D, bo + l * D,
             delta_f, delta2_f, D, nullptr, 0, D, D, 0, 2);
        resln_kernel<<<MTOK / 4, 256, 0, stream>>>(x_b, delta_f, delta2_f,
                                                   g1 + l * D, bt1 + l * D, x_b);
        gemm(x_b, D, w1_b + (size_t)l * FFD * D, D, b1 + l * FFD,
             nullptr, nullptr, 0, h1_b, FFD, FFD, D, 1, 1);
        gemm(h1_b, FFD, w2_b + (size_t)l * D * FFD, FFD, b2 + l * D,
             delta_f, delta2_f, D, nullptr, 0, D, FFD, 0, 2);
        resln_kernel<<<MTOK / 4, 256, 0, stream>>>(x_b, delta_f, delta2_f,
                                                   g2 + l * D, bt2 + l * D, x_b);
    }

    // output head
    gemm(x_b, D, woutp_b, D, b_outp, nullptr, nullptr, 0, hout_b, HID, HID, D, 0, 1);
    gemm(hout_b, HID, wa_b, HID, ba_f, (float*)d_out, nullptr, NOUT, nullptr, 0, NOUT, HID, 0, 1);
}